// Round 11
// baseline (350.360 us; speedup 1.0000x reference)
//
#include <hip/hip_runtime.h>

typedef __bf16 bf16;
typedef __bf16 bf16x4 __attribute__((ext_vector_type(4)));
typedef __bf16 bf16x8 __attribute__((ext_vector_type(8)));
typedef float  floatx4 __attribute__((ext_vector_type(4)));

#define L_SEQ   2048
#define C_SEQ   256
#define S_SEQ   2304
#define NBATCH  4
#define NHEAD   16
#define DHEAD   64
#define DMODEL  1024
#define RMS_EPS 1.1920928955078125e-07f
#define LIN_EPS 1e-6f

// async global->LDS, 16B per lane; LDS dest must be wave-uniform (+lane*16)
__device__ __forceinline__ void gload_lds16(const void* g, void* l) {
  __builtin_amdgcn_global_load_lds(
      (const __attribute__((address_space(1))) void*)g,
      (__attribute__((address_space(3))) void*)l, 16, 0, 0);
}

// ---------------------------------------------------------------- prep jobs
// 64x64 transpose tile: float4 reads, LDS stored transposed, bf16x4 writes
// (128 B contiguous dst segments).
__device__ __forceinline__ void transpose_job64(
    const float* __restrict__ src, bf16* __restrict__ dst,
    int R, int C, int tb, bf16 (*tile)[65]) {
  int tilesx = C >> 6;
  int c0 = (tb % tilesx) * 64, r0 = (tb / tilesx) * 64;
  int tx = threadIdx.x & 15, ty = threadIdx.x >> 4;   // 16 cols x 16 rows
#pragma unroll
  for (int it = 0; it < 4; it++) {
    int rl = ty + it * 16;
    floatx4 v = *(const floatx4*)(src + (size_t)(r0 + rl) * C + c0 + tx * 4);
#pragma unroll
    for (int j = 0; j < 4; j++) tile[tx * 4 + j][rl] = (bf16)v[j];  // [col][row]
  }
  __syncthreads();
#pragma unroll
  for (int it = 0; it < 4; it++) {
    int i = ty + it * 16;                              // dst row = src col
    bf16x4 o = *(const bf16x4*)&tile[i][tx * 4];
    *(bf16x4*)(dst + (size_t)(c0 + i) * R + r0 + tx * 4) = o;
  }
}

__device__ __forceinline__ void convert_job(
    const float* __restrict__ src, bf16* __restrict__ dst, int tb) {
  size_t i = ((size_t)tb * 256 + threadIdx.x) * 8;
  floatx4 a = *(const floatx4*)(src + i);
  floatx4 b = *(const floatx4*)(src + i + 4);
  bf16x8 o;
#pragma unroll
  for (int j = 0; j < 4; j++) { o[j] = (bf16)a[j]; o[4 + j] = (bf16)b[j]; }
  *(bf16x8*)(dst + i) = o;
}

// prep: only what the QKV GEMM (launch 2) depends on, plus rope/anymask.
__global__ __launch_bounds__(256) void prep(
    const float* __restrict__ Wqkv, const float* __restrict__ cWqkv,
    const float* __restrict__ x, const float* __restrict__ ctx,
    const int* __restrict__ mask, const int* __restrict__ spos,
    bf16* __restrict__ WqkvT, bf16* __restrict__ cWqkvT,
    bf16* __restrict__ xbf, bf16* __restrict__ cbf,
    float* __restrict__ rope, int* __restrict__ anym) {
  __shared__ bf16 tile[64][65];
  __shared__ int sh;
  int b = blockIdx.x;
  if (b < 768) { transpose_job64(Wqkv, WqkvT, 1024, 3072, b, tile); return; }
  b -= 768;
  if (b < 768) { transpose_job64(cWqkv, cWqkvT, 1024, 3072, b, tile); return; }
  b -= 768;
  if (b < 4096) { convert_job(x, xbf, b); return; }
  b -= 4096;
  if (b < 512) { convert_job(ctx, cbf, b); return; }
  b -= 512;
  if (b < 2048) {
    // rope table: token = b*4 + t/64 (x tokens only), j = t&63, fi = j>>1
    int t = threadIdx.x;
    int tok = b * 4 + (t >> 6);
    int bb = tok >> 11, s = tok & 2047;
    int j = t & 63, fi = j >> 1;
    float ang = (float)(spos[bb] + s) * expf((float)fi * -0.28782313662425572f);
    rope[(size_t)tok * 64 + j] = (j & 1) ? sinf(ang) : cosf(ang);
    return;
  }
  b -= 2048;
  // anymask: any(mask[b][0][:])
  int a = 0;
  size_t base = (size_t)b * L_SEQ * L_SEQ;
  for (int j = threadIdx.x; j < L_SEQ; j += 256) a |= mask[base + j];
  if (threadIdx.x == 0) sh = 0;
  __syncthreads();
  if (a) atomicOr(&sh, 1);
  __syncthreads();
  if (threadIdx.x == 0) anym[b] = sh;
}

// ---------------------------------------------------------------- QKV GEMM
// 256x256 tile, BK=32, 8 waves (2Mx4N, wave tile 128x64), 64 KiB dbuf LDS
// -> 2 blocks/CU -> all 432 blocks co-resident (ONE generation; fixes the
// R7 structure's 2-generation + fill/drain losses). Counted-vmcnt 2-deep
// pipeline, 2 barriers/tile:
//   {ds_read 12 frags; lgkmcnt(0); sched_barrier; s_barrier;
//    stage(t+2 -> buf just consumed, 4 loads/wave); setprio+32 MFMA;
//    vmcnt(4) [= t+1 landed, t+2 in flight]; s_barrier}
// vmcnt ledger: prologue stages t0,t1 (8 loads/wave), vmcnt(4)=t0 landed.
// Steady state 8 outstanding, wait to 4. vmcnt(0) only in the tail.
// Rotation bank swizzle (R5-verified, 64B rows): content slot
// ((l&3)-((l>>3)&3))&3 on the pre-swizzled global source; read slot
// (l4+((l16>>1)&3))&3. Scatter epilogue identical to R7/R9.
__global__ __launch_bounds__(512) void gemm_qkv_bk32(
    const bf16* __restrict__ A1, const bf16* __restrict__ A2,
    const bf16* __restrict__ B1t, const bf16* __restrict__ B2t,
    const float* __restrict__ bias1, const float* __restrict__ bias2,
    bf16* __restrict__ qs, bf16* __restrict__ ks, bf16* __restrict__ vs,
    int K, int ybound, int rpb1, int soff1, int rpb2, int soff2) {
  __shared__ bf16 As[2][256 * 32];   // 16 KiB per buf
  __shared__ bf16 Bs[2][256 * 32];

  int nwg = gridDim.x * gridDim.y;
  int wg = blockIdx.y * gridDim.x + blockIdx.x;
  int cpx = nwg >> 3;
  wg = (wg & 7) * cpx + (wg >> 3);          // XCD swizzle (nwg % 8 == 0)
  int bx = wg % gridDim.x, by = wg / gridDim.x;
  int n0 = bx * 256;
  const bf16 *Ap, *Bt;
  const float* bias;
  int m0, rpb, soff;
  if (by < ybound) {
    Ap = A1; Bt = B1t; bias = bias1; m0 = by * 256; rpb = rpb1; soff = soff1;
  } else {
    Ap = A2; Bt = B2t; bias = bias2; m0 = (by - ybound) * 256; rpb = rpb2; soff = soff2;
  }

  int t = threadIdx.x, lane = t & 63, w = t >> 6;
  int wr = w >> 2, wc = w & 3;              // wave tile: rows wr*128, cols wc*64
  int l16 = lane & 15, l4 = lane >> 4;

  // staging: wave w covers A rows [w*32, w*32+32) (chunks 2w,2w+1) and the
  // same B rows; chunk = 16 rows x 64 B; lane l -> row c*16+(l>>2), physical
  // slot l&3, content = logical slot ((l&3)-((l>>3)&3))&3 (rotation inverse).
  int crow = w * 32 + (lane >> 2);
  int scol = ((((lane & 3) - ((lane >> 3) & 3)) & 3)) << 3;
  const bf16* Ab = Ap + (size_t)(m0 + crow) * K + scol;
  const bf16* Bb = Bt + (size_t)(n0 + crow) * K + scol;

  auto stage = [&](int buf, int kb) {
#pragma unroll
    for (int j = 0; j < 2; j++) {
      gload_lds16(Ab + (size_t)(j * 16) * K + kb, (char*)As[buf] + (w * 2 + j) * 1024);
      gload_lds16(Bb + (size_t)(j * 16) * K + kb, (char*)Bs[buf] + (w * 2 + j) * 1024);
    }
  };

  // ds_read: logical slot l4 at row (base16 + l16) -> physical slot
  // (l4 + (l16>>1)) & 3.
  int co = ((l4 + ((l16 >> 1) & 3)) & 3) << 3;
  int rba = (wr * 128 + l16) * 32 + co;   // + mt*512
  int rbb = (wc * 64 + l16) * 32 + co;    // + nt*512

  floatx4 acc[8][4] = {};
  int NT = K >> 5;
  stage(0, 0);
  stage(1, 32);
  asm volatile("s_waitcnt vmcnt(4)" ::: "memory");   // tile 0 landed
  __builtin_amdgcn_s_barrier();

  for (int tt = 0; tt < NT; ++tt) {
    int p = tt & 1;
    // 1) fragment reads into registers
    bf16x8 bfr[4], afr[8];
#pragma unroll
    for (int nt = 0; nt < 4; nt++) bfr[nt] = *(const bf16x8*)&Bs[p][rbb + nt * 512];
#pragma unroll
    for (int mt = 0; mt < 8; mt++) afr[mt] = *(const bf16x8*)&As[p][rba + mt * 512];
    // 2) all LDS reads complete before anyone overwrites this buffer
    asm volatile("s_waitcnt lgkmcnt(0)" ::: "memory");
    __builtin_amdgcn_sched_barrier(0);
    __builtin_amdgcn_s_barrier();
    // 3) stage t+2 into the buffer just consumed
    if (tt + 2 < NT) stage(p, (tt + 2) << 5);
    // 4) MFMA cluster
    __builtin_amdgcn_s_setprio(1);
#pragma unroll
    for (int mt = 0; mt < 8; mt++)
#pragma unroll
      for (int nt = 0; nt < 4; nt++)
        acc[mt][nt] = __builtin_amdgcn_mfma_f32_16x16x32_bf16(afr[mt], bfr[nt], acc[mt][nt], 0, 0, 0);
    __builtin_amdgcn_s_setprio(0);
    // 5) counted drain: t+1's 4 loads landed (t+2's 4 may remain in flight)
    if (tt + 2 < NT) asm volatile("s_waitcnt vmcnt(4)" ::: "memory");
    else             asm volatile("s_waitcnt vmcnt(0)" ::: "memory");
    __builtin_amdgcn_s_barrier();
  }

  // epilogue: scatter; D[row=(l>>4)*4+r][col=l&15] per 16x16 tile
#pragma unroll
  for (int mt = 0; mt < 8; mt++)
#pragma unroll
    for (int nt = 0; nt < 4; nt++) {
      int col = n0 + wc * 64 + nt * 16 + l16;
      float bval = bias[col];
      int which = col >> 10;
      int h = (col >> 6) & 15;
      int dh = col & 63;
      int rmask = (1 << rpb) - 1;
      if (which == 2) {
        int rw0 = m0 + wr * 128 + mt * 16 + l4 * 4;
        int b = rw0 >> rpb;
        int s = soff + (rw0 & rmask);
        bf16x4 o;
#pragma unroll
        for (int r = 0; r < 4; r++) o[r] = (bf16)(acc[mt][nt][r] + bval);
        *(bf16x4*)(vs + ((size_t)(b * NHEAD + h) * DHEAD + dh) * S_SEQ + s) = o;
      } else {
        bf16* dst = which == 0 ? qs : ks;
#pragma unroll
        for (int r = 0; r < 4; r++) {
          int rw = m0 + wr * 128 + mt * 16 + l4 * 4 + r;
          int b = rw >> rpb;
          int s = soff + (rw & rmask);
          dst[((size_t)(b * NHEAD + h) * S_SEQ + s) * DHEAD + dh] =
              (bf16)(acc[mt][nt][r] + bval);
        }
      }
    }
}

// ---------------------------------------------------------------- out GEMM
// PROVEN R5 config: 128x128 tile, BK=32, 4 waves, 2-phase dbuf, rotation
// bank swizzle, ~3 blocks/CU. (See R5 notes.)
template <bool SCATTER>
__global__ __launch_bounds__(256) void gemm_bias(
    const bf16* __restrict__ A1, const bf16* __restrict__ A2,
    const bf16* __restrict__ B1t, const bf16* __restrict__ B2t,
    const float* __restrict__ bias1, const float* __restrict__ bias2,
    bf16* __restrict__ C1, bf16* __restrict__ C2,
    bf16* __restrict__ qs, bf16* __restrict__ ks, bf16* __restrict__ vs,
    int N, int K, int ybound,
    int rpb1, int soff1, int rpb2, int soff2) {
  __shared__ bf16 As[2][4096];
  __shared__ bf16 Bs[2][4096];
  int nwg = gridDim.x * gridDim.y;
  int wg = blockIdx.y * gridDim.x + blockIdx.x;
  int cpx = nwg >> 3;
  wg = (wg & 7) * cpx + (wg >> 3);
  int bx = wg % gridDim.x, by = wg / gridDim.x;
  int n0 = bx * 128;
  const bf16 *Ap, *Bt;
  const float* bias;
  bf16* Cp;
  int m0, rpb, soff;
  if (by < ybound) {
    Ap = A1; Bt = B1t; bias = bias1; Cp = C1;
    m0 = by * 128; rpb = rpb1; soff = soff1;
  } else {
    Ap = A2; Bt = B2t; bias = bias2; Cp = C2;
    m0 = (by - ybound) * 128; rpb = rpb2; soff = soff2;
  }
  int t = threadIdx.x, lane = t & 63, w = t >> 6;
  int wm = (w & 1) * 64, wn = (w >> 1) * 64;
  int l16 = lane & 15, l4 = lane >> 4;
  int crow = w * 32 + (lane >> 2);
  int scol = ((((lane & 3) - ((lane >> 3) & 3)) & 3)) << 3;
  const bf16* Ab = Ap + (size_t)(m0 + crow) * K + scol;
  const bf16* Bb = Bt + (size_t)(n0 + crow) * K + scol;
  auto stage = [&](int buf, int kb) {
#pragma unroll
    for (int j = 0; j < 2; j++) {
      gload_lds16(Ab + (size_t)(j * 16) * K + kb, (char*)As[buf] + (w * 2 + j) * 1024);
      gload_lds16(Bb + (size_t)(j * 16) * K + kb, (char*)Bs[buf] + (w * 2 + j) * 1024);
    }
  };
  int co = ((l4 + ((l16 >> 1) & 3)) & 3) << 3;
  int rba = (wm + l16) * 32 + co;
  int rbb = (wn + l16) * 32 + co;
  floatx4 acc[4][4] = {};
  stage(0, 0);
  __syncthreads();
  int NTt = K >> 5;
  for (int tt = 0; tt < NTt; ++tt) {
    int p = tt & 1;
    if (tt + 1 < NTt) stage(p ^ 1, (tt + 1) << 5);
    bf16x8 bfr[4];
#pragma unroll
    for (int nt = 0; nt < 4; nt++) bfr[nt] = *(const bf16x8*)&Bs[p][rbb + nt * 512];
    __builtin_amdgcn_s_setprio(1);
#pragma unroll
    for (int mt = 0; mt < 4; mt++) {
      bf16x8 a = *(const bf16x8*)&As[p][rba + mt * 512];
#pragma unroll
      for (int nt = 0; nt < 4; nt++)
        acc[mt][nt] = __builtin_amdgcn_mfma_f32_16x16x32_bf16(a, bfr[nt], acc[mt][nt], 0, 0, 0);
    }
    __builtin_amdgcn_s_setprio(0);
    __syncthreads();
  }
#pragma unroll
  for (int mt = 0; mt < 4; mt++)
#pragma unroll
    for (int nt = 0; nt < 4; nt++) {
      int col = n0 + wn + nt * 16 + l16;
      float bval = bias[col];
      if constexpr (SCATTER) {
        int which = col >> 10;
        int h = (col >> 6) & 15;
        int dh = col & 63;
        int rmask = (1 << rpb) - 1;
        if (which == 2) {
          int rw0 = m0 + wm + mt * 16 + l4 * 4;
          int b = rw0 >> rpb;
          int s = soff + (rw0 & rmask);
          bf16x4 o;
#pragma unroll
          for (int r = 0; r < 4; r++) o[r] = (bf16)(acc[mt][nt][r] + bval);
          *(bf16x4*)(vs + ((size_t)(b * NHEAD + h) * DHEAD + dh) * S_SEQ + s) = o;
        } else {
          bf16* dst = which == 0 ? qs : ks;
#pragma unroll
          for (int r = 0; r < 4; r++) {
            int rw = m0 + wm + mt * 16 + l4 * 4 + r;
            int b = rw >> rpb;
            int s = soff + (rw & rmask);
            dst[((size_t)(b * NHEAD + h) * S_SEQ + s) * DHEAD + dh] =
                (bf16)(acc[mt][nt][r] + bval);
          }
        }
      } else {
#pragma unroll
        for (int r = 0; r < 4; r++) {
          int rw = m0 + wm + mt * 16 + l4 * 4 + r;
          Cp[(size_t)rw * N + col] = (bf16)(acc[mt][nt][r] + bval);
        }
      }
    }
}

// ---------------------------------------------------------------- qkv post
// 2 tokens per block, 128 threads/token, 16 B/lane. Extra block ranges
// absorb work only needed by LATER launches.
__global__ __launch_bounds__(256) void qkv_post(
    bf16* __restrict__ qs, bf16* __restrict__ ks,
    const int* __restrict__ mask, const float* __restrict__ rope,
    const int* __restrict__ anym,
    const float* __restrict__ g_q, const float* __restrict__ g_k,
    const float* __restrict__ cg_q, const float* __restrict__ cg_k,
    const float* __restrict__ Wout, const float* __restrict__ cWout,
    bf16* __restrict__ WoutT, bf16* __restrict__ cWoutT,
    float* __restrict__ vkw) {
  __shared__ bf16 tile[64][65];
  __shared__ float red[8];
  int blk = blockIdx.x, t = threadIdx.x;
  if (blk >= 4608) {
    int b = blk - 4608;
    if (b < 256) { transpose_job64(Wout, WoutT, 1024, 1024, b, tile); return; }
    b -= 256;
    if (b < 256) { transpose_job64(cWout, cWoutT, 1024, 1024, b, tile); return; }
    b -= 256;
    int i = b * 1024 + t * 4;
    *(floatx4*)(vkw + i) = floatx4{0.f, 0.f, 0.f, 0.f};
    return;
  }
  int tt = t & 127, tsel = t >> 7;
  int g = blk * 2 + tsel;                       // token id (x: <8192, ctx rest)
  bool is_ctx = g >= NBATCH * L_SEQ;
  int b, s;
  const float *gq, *gk;
  float mval;
  if (!is_ctx) {
    b = g >> 11;
    int l = g & 2047;
    s = l;
    mval = mask[(size_t)b * L_SEQ * L_SEQ + l] ? 1.f : 0.f;  // mask[b][0][l]
    gq = g_q; gk = g_k;
  } else {
    int gg = g - NBATCH * L_SEQ;
    b = gg >> 8;
    s = L_SEQ + (gg & 255);
    mval = anym[b] ? 1.f : 0.f;
    gq = cg_q; gk = cg_k;
  }
  int d0 = tt * 8;
  int h = tt >> 3, dh = (tt & 7) * 8;           // h*64+dh == d0
  size_t base = ((size_t)(b * NHEAD + h) * S_SEQ + s) * DHEAD + dh;
  bf16x8 q8 = *(const bf16x8*)(qs + base);
  bf16x8 k8 = *(const bf16x8*)(ks + base);
  float qv[8], kv[8], pq = 0.f, pk = 0.f;
#pragma unroll
  for (int i = 0; i < 8; i++) {
    qv[i] = (float)q8[i]; kv[i] = (float)k8[i];
    pq += qv[i] * qv[i];  pk += kv[i] * kv[i];
  }
  int w = t >> 6;                                // wave id 0..3
  for (int off = 32; off > 0; off >>= 1) {
    pq += __shfl_down(pq, off, 64);
    pk += __shfl_down(pk, off, 64);
  }
  if ((t & 63) == 0) { red[w] = pq; red[4 + w] = pk; }
  __syncthreads();
  float sq = red[tsel * 2] + red[tsel * 2 + 1];
  float sk = red[4 + tsel * 2] + red[4 + tsel * 2 + 1];
  float scq = rsqrtf(sq * (1.f / DMODEL) + RMS_EPS);
  float sck = rsqrtf(sk * (1.f / DMODEL) + RMS_EPS);
#pragma unroll
  for (int i = 0; i < 8; i++) {
    qv[i] *= scq * gq[d0 + i];
    kv[i] *= sck * gk[d0 + i];
  }
  if (!is_ctx) {
    // table: 64 entries PER TOKEN indexed by HEAD dim dh (cos even, sin odd)
    floatx4 ta = *(const floatx4*)&rope[((size_t)g) * 64 + dh];
    floatx4 tb = *(const floatx4*)&rope[((size_t)g) * 64 + dh + 4];
#pragma unroll
    for (int pr = 0; pr < 4; pr++) {
      float cc = pr < 2 ? ta[2 * pr] : tb[2 * (pr - 2)];
      float ss = pr < 2 ? ta[2 * pr + 1] : tb[2 * (pr - 2) + 1];
      float t0 = qv[2 * pr], t1 = qv[2 * pr + 1];
      qv[2 * pr]     = t0 * cc - t1 * ss;
      qv[2 * pr + 1] = t0 * ss + t1 * cc;
      t0 = kv[2 * pr]; t1 = kv[2 * pr + 1];
      kv[2 * pr]     = t0 * cc - t1 * ss;
      kv[2 * pr + 1] = t0 * ss + t1 * cc;
    }
  }
  bf16x8 qo, ko;
#pragma unroll
  for (int i = 0; i < 8; i++) {
    qo[i] = (bf16)fmaxf(qv[i], 0.f);
    ko[i] = (bf16)(fmaxf(kv[i], 0.f) * mval);
  }
  *(bf16x8*)(qs + base) = qo;
  *(bf16x8*)(ks + base) = ko;
}

// ---------------------------------------------------------------- vk (MFMA)
#define VK_CH   12
#define VK_SPAN (S_SEQ / VK_CH)   // 192 = 6 K-steps of 32
__global__ __launch_bounds__(256) void vk_mfma(
    const bf16* __restrict__ vT, const bf16* __restrict__ kf,
    float* __restrict__ vk) {
  __shared__ bf16 Vs[2][64][40];
  __shared__ bf16 Ks[2][64][40];   // Ks[d][s]
  int bh = blockIdx.x / VK_CH, chunk = blockIdx.x % VK_CH;
  int t = threadIdx.x, lane = t & 63, w = t >> 6;
  int l16 = lane & 15, l4 = lane >> 4;
  const bf16* vp = vT + (size_t)bh * DHEAD * S_SEQ;
  const bf16* kp = kf + (size_t)bh * S_SEQ * DHEAD;
  int s_begin = chunk * VK_SPAN;
  int ve = t >> 2, vso = (t & 3) * 8;        // v staging: row e, col offset
  int ks_s = t & 31, kd0 = (t >> 5) * 8;     // kf staging: s-slice, d-octet
  floatx4 acc[4] = {};
  float dsum[8] = {};
  bf16x8 vv = *(const bf16x8*)(vp + (size_t)ve * S_SEQ + s_begin + vso);
  bf16x8 kv = *(const bf16x8*)(kp + (size_t)(s_begin + ks_s) * DHEAD + kd0);
  for (int st = 0; st < VK_SPAN; st += 32) {
    int cur = (st >> 5) & 1;
    *(bf16x8*)&Vs[cur][ve][vso] = vv;
#pragma unroll
    for (int j = 0; j < 8; j++) {
      Ks[cur][kd0 + j][ks_s] = kv[j];
      dsum[j] += (float)kv[j];
    }
    if (st + 32 < VK_SPAN) {
      int s0 = s_begin + st + 32;
      vv = *(const bf16x8*)(vp + (size_t)ve * S_SEQ + s0 + vso);
      kv = *(const bf16x8*)(kp + (size_t)(s0 + ks_s) * DHEAD + kd0);
    }
    __syncthreads();
    bf16x8 af = *(const bf16x8*)&Vs[cur][w * 16 + l16][l4 * 8];
#pragma unroll
    for (int nt = 0; nt < 4; nt++) {
      bf16x8 bfr = *(const bf16x8*)&Ks[cur][nt * 16 + l16][l4 * 8];
      acc[nt] = __builtin_amdgcn_mfma_f32_16x16x32_bf16(af, bfr, acc[nt], 0, 0, 0);
    }
  }
  float* vkbh = vk + (size_t)bh * 65 * 64;
#pragma unroll
  for (int nt = 0; nt < 4; nt++)
#pragma unroll
    for (int r = 0; r < 4; r++)
      atomicAdd(&vkbh[(w * 16 + l4 * 4 + r) * 64 + nt * 16 + l16], acc[nt][r]);
#pragma unroll
  for (int j = 0; j < 8; j++)
#pragma unroll
    for (int off = 16; off > 0; off >>= 1)
      dsum[j] += __shfl_down(dsum[j], off, 32);
  if ((lane & 31) == 0)
#pragma unroll
    for (int j = 0; j < 8; j++)
      atomicAdd(&vkbh[64 * 64 + kd0 + j], dsum[j]);
}

// ---------------------------------------------------------------- res + div
__global__ __launch_bounds__(256) void res_attn(
    const bf16* __restrict__ qf, const float* __restrict__ vk,
    bf16* __restrict__ attn_x, bf16* __restrict__ attn_c) {
  __shared__ bf16 Bs[80][72];
  __shared__ float sden[256];
  int bh = blockIdx.x / 9, mblk = blockIdx.x % 9;
  int b = bh >> 4, h = bh & 15;
  int t = threadIdx.x, lane = t & 63, w = t >> 6;
  const float* vkp = vk + (size_t)bh * 65 * 64;
  for (int i = t; i < 80 * 64; i += 256) {
    int e = i >> 6, d = i & 63;
    Bs[e][d] = (bf16)(e < 65 ? vkp[i] : 0.f);
  }
  __syncthreads();
  int l16 = lane & 15, l4 = lane >> 4;
  const bf16* qbase = qf + (size_t)bh * S_SEQ * DHEAD;
  int q0w = mblk * 256 + w * 64;

  floatx4 acc[4][5] = {};
  bf16x8 af[4][2], bfr[5][2];
#pragma unroll
  for (int mt = 0; mt < 4; mt++) {
    int q = q0w + mt * 16 + l16;
    af[mt][0] = *(const bf16x8*)(qbase + (size_t)q * 64 + l4 * 8);
    af[mt][1] = *(const bf16x8*)(qbase + (size_t)q * 64 + 32 + l4 * 8);
  }
#pragma unroll
  for (int nt = 0; nt < 5; nt++) {
    bfr[nt][0] = *(const bf16x8*)&Bs[nt * 16 + l16][l4 * 8];
    bfr[nt][1] = *(const bf16x8*)&Bs[nt * 16 + l16][32 + l4 * 8];
  }
#pragma unroll
  for (int mt = 0; mt < 4; mt++)
#pragma unroll
    for (int nt = 0; nt < 5; nt++) {
      acc[mt][nt] = __builtin_amdgcn_mfma_f32_16x16x32_bf16(af[mt][0], bfr[nt][0], acc[mt][nt], 0, 0, 0);
      acc[mt][nt] = __builtin_amdgcn_mfma_f32_16x16x32_bf16(af[mt][1], bfr[nt][1], acc[mt][nt], 0, 0, 0);
    }
  // denominator: e=64 = col 0 of n-tile 4 (lanes with l16==0)
  if (l16 == 0) {
#pragma unroll
    for (int mt = 0; mt < 4; mt++)
#pragma unroll
      for (int r = 0; r < 4; r++)
        sden[w * 64 + mt * 16 + l4 * 4 + r] = acc[mt][4][r];
  }
  __syncthreads();
#pragma unroll
  for (int mt = 0; mt < 4; mt++)
#pragma unroll
    for (int r = 0; r < 4; r++) {
      float den = sden[w * 64 + mt * 16 + l4 * 4 + r] + LIN_EPS;
      float rden = 1.f / den;
      int q = q0w + mt * 16 + l4 * 4 + r;
#pragma unroll
      for (int nt = 0; nt < 4; nt++) {
        int dcol = nt * 16 + l16;
        float a = acc[mt][nt][r] * rden;
        if (q < L_SEQ)
          attn_x[((size_t)b * L_SEQ + q) * DMODEL + h * DHEAD + dcol] = (bf16)a;
        else
          attn_c[((size_t)b * C_SEQ + (q - L_SEQ)) * DMODEL + h * DHEAD + dcol] = (bf16)a;
      }
    }
}

// ---------------------------------------------------------------- final norm
// 2 rows/block, 128 threads/row, 16 B/lane in, 32 B/lane out (f32).
__global__ __launch_bounds__(256) void final_norm(
    const bf16* __restrict__ y_x, const bf16* __restrict__ y_c,
    const float* __restrict__ g_out, const float* __restrict__ cg_out,
    float* __restrict__ out) {
  __shared__ float red[8];
  int t = threadIdx.x;
  int tt = t & 127, tsel = t >> 7;
  int g = blockIdx.x * 2 + tsel;
  const bf16* src;
  const float* gv;
  if (g < NBATCH * L_SEQ) {
    src = y_x + (size_t)g * DMODEL; gv = g_out;
  } else {
    int gg = g - NBATCH * L_SEQ;
    src = y_c + (size_t)gg * DMODEL; gv = cg_out;
  }
  float* dst = out + (size_t)g * DMODEL;
  int d0 = tt * 8;
  bf16x8 y8 = *(const bf16x8*)(src + d0);
  float yv[8], p = 0.f;
#pragma unroll
  for (int i = 0; i < 8; i++) { yv[i] = (float)y8[i]; p += yv[i] * yv[i]; }
  int w = t >> 6;
  for (int off = 32; off > 0; off >>= 1) p += __shfl_down(p, off, 64);
  if ((t & 63) == 0) red[w] = p;
  __syncthreads();
  float ssum = red[tsel * 2] + red[tsel * 2 + 1];
  float sc = rsqrtf(ssum * (1.f / DMODEL) + RMS_EPS);
  floatx4 o0, o1;
#pragma unroll
  for (int i = 0; i < 4; i++) {
    o0[i] = yv[i] * sc * gv[d0 + i];
    o1[i] = yv[4 + i] * sc * gv[d0 + 4 + i];
  }
  *(floatx4*)(dst + d0) = o0;
  *(floatx4*)(dst + d0 + 4) = o1;
}

// ---------------------------------------------------------------- launch
extern "C" void kernel_launch(void* const* d_in, const int* in_sizes, int n_in,
                              void* d_out, int out_size, void* d_ws, size_t ws_size,
                              hipStream_t stream) {
  const float* x      = (const float*)d_in[0];
  const float* ctx    = (const float*)d_in[1];
  const int*   mask   = (const int*)d_in[2];
  const int*   spos   = (const int*)d_in[3];
  const float* Wqkv   = (const float*)d_in[4];
  const float* bqkv   = (const float*)d_in[5];
  const float* g_q    = (const float*)d_in[6];
  const float* g_k    = (const float*)d_in[7];
  const float* cWqkv  = (const float*)d_in[8];
  const float* cbqkv  = (const float*)d_in[9];
  const float* cg_q   = (const float*)d_in[10];
  const float* cg_k   = (const float*)d_in[11];
  const float* Wout   = (const float*)d_in[12];
  const float* bout   = (const float*)d_in[13];
  const float* g_out  = (const float*)d_in[14];
  const float* cWout  = (const float*)d_in[15];
  const float* cbout  = (const float*)d_in[16];
  const float* cg_out = (const float*)d_in[17];

  char* wsp = (char*)d_ws;
  size_t off = 0;
  auto alloc = [&](size_t bytes) -> void* {
    void* p = wsp + off;
    off += (bytes + 255) & ~(size_t)255;
    return p;
  };
  bf16* WqkvT  = (bf16*)alloc((size_t)3072 * 1024 * 2);
  bf16* cWqkvT = (bf16*)alloc((size_t)3072 * 1024 * 2);
  bf16* WoutT  = (bf16*)alloc((size_t)1024 * 1024 * 2);
  bf16* cWoutT = (bf16*)alloc((size_t)1024 * 1024 * 2);
  bf16* xbf    = (bf16*)alloc((size_t)NBATCH * L_SEQ * DMODEL * 2);
  bf16* cbf    = (bf16*)alloc((size_t)NBATCH * C_SEQ * DMODEL * 2);
  const size_t SLAB = (size_t)NBATCH * NHEAD * S_SEQ * DHEAD;  // 9,437,184
  bf16* qfs    = (bf16*)alloc(SLAB * 2);
  bf16* kfs    = (bf16*)alloc(SLAB * 2);
  bf16* vfs    = (bf16*)alloc(SLAB * 2);   // holds vT [bh][d][s]
  float* vkw   = (float*)alloc((size_t)64 * 65 * 64 * 4);
  float* rope  = (float*)alloc((size_t)NBATCH * L_SEQ * 64 * 4);
  int* anym    = (int*)alloc(256);
  // attn aliases kf slab (dead after vk_mfma); y aliases v slab.
  bf16* attn_x = kfs;
  bf16* attn_c = kfs + (size_t)NBATCH * L_SEQ * DMODEL;
  bf16* y_x    = vfs;
  bf16* y_c    = vfs + (size_t)NBATCH * L_SEQ * DMODEL;

  // 1) prep (QKV-critical only): Wqkv/cWqkv transposes, converts, rope, anymask
  prep<<<8196, 256, 0, stream>>>(Wqkv, cWqkv, x, ctx, mask, spos,
                                 WqkvT, cWqkvT, xbf, cbf, rope, anym);

  // 2) QKV projections: 256^2 BK=32, 2 blocks/CU, counted-vmcnt pipeline
  gemm_qkv_bk32<<<dim3(12, 36), 512, 0, stream>>>(
      xbf, cbf, WqkvT, cWqkvT, bqkv, cbqkv,
      qfs, kfs, vfs, 1024, 32, 11, 0, 8, L_SEQ);

  // 3) qkv post (16 B/lane) + deferred Wout/cWout transposes + vkw zero
  qkv_post<<<5380, 256, 0, stream>>>(
      qfs, kfs, mask, rope, anym, g_q, g_k, cg_q, cg_k,
      Wout, cWout, WoutT, cWoutT, vkw);

  // 4) vk = vT kf via MFMA
  vk_mfma<<<64 * VK_CH, 256, 0, stream>>>(vfs, kfs, vkw);

  // 5) res = qf vk^T, divide, scatter to token-major (B,S,D)
  res_attn<<<576, 256, 0, stream>>>(qfs, vkw, attn_x, attn_c);

  // 6) output projections (x + ctx in one launch), proven 128^2 2-phase
  gemm_bias<false><<<dim3(8, 72), 256, 0, stream>>>(
      attn_x, attn_c, WoutT, cWoutT, bout, cbout, y_x, y_c,
      nullptr, nullptr, nullptr, 1024, 1024, 64, 0, 0, 0, 0);

  // 7) final rmsnorm -> FLOAT32 d_out (x_out rows then c_out rows)
  final_norm<<<4608, 256, 0, stream>>>(
      y_x, y_c, g_out, cg_out, (float*)d_out);
}

// Round 12
// 344.651 us; speedup vs baseline: 1.0166x; 1.0166x over previous
//
#include <hip/hip_runtime.h>

typedef __bf16 bf16;
typedef __bf16 bf16x4 __attribute__((ext_vector_type(4)));
typedef __bf16 bf16x8 __attribute__((ext_vector_type(8)));
typedef float  floatx4 __attribute__((ext_vector_type(4)));

#define L_SEQ   2048
#define C_SEQ   256
#define S_SEQ   2304
#define NBATCH  4
#define NHEAD   16
#define DHEAD   64
#define DMODEL  1024
#define RMS_EPS 1.1920928955078125e-07f
#define LIN_EPS 1e-6f

// async global->LDS, 16B per lane; LDS dest must be wave-uniform (+lane*16)
__device__ __forceinline__ void gload_lds16(const void* g, void* l) {
  __builtin_amdgcn_global_load_lds(
      (const __attribute__((address_space(1))) void*)g,
      (__attribute__((address_space(3))) void*)l, 16, 0, 0);
}

// ---------------------------------------------------------------- prep jobs
// 64x64 transpose tile: float4 reads, LDS stored transposed, bf16x4 writes
// (128 B contiguous dst segments).
__device__ __forceinline__ void transpose_job64(
    const float* __restrict__ src, bf16* __restrict__ dst,
    int R, int C, int tb, bf16 (*tile)[65]) {
  int tilesx = C >> 6;
  int c0 = (tb % tilesx) * 64, r0 = (tb / tilesx) * 64;
  int tx = threadIdx.x & 15, ty = threadIdx.x >> 4;   // 16 cols x 16 rows
#pragma unroll
  for (int it = 0; it < 4; it++) {
    int rl = ty + it * 16;
    floatx4 v = *(const floatx4*)(src + (size_t)(r0 + rl) * C + c0 + tx * 4);
#pragma unroll
    for (int j = 0; j < 4; j++) tile[tx * 4 + j][rl] = (bf16)v[j];  // [col][row]
  }
  __syncthreads();
#pragma unroll
  for (int it = 0; it < 4; it++) {
    int i = ty + it * 16;                              // dst row = src col
    bf16x4 o = *(const bf16x4*)&tile[i][tx * 4];
    *(bf16x4*)(dst + (size_t)(c0 + i) * R + r0 + tx * 4) = o;
  }
}

__device__ __forceinline__ void convert_job(
    const float* __restrict__ src, bf16* __restrict__ dst, int tb) {
  size_t i = ((size_t)tb * 256 + threadIdx.x) * 8;
  floatx4 a = *(const floatx4*)(src + i);
  floatx4 b = *(const floatx4*)(src + i + 4);
  bf16x8 o;
#pragma unroll
  for (int j = 0; j < 4; j++) { o[j] = (bf16)a[j]; o[4 + j] = (bf16)b[j]; }
  *(bf16x8*)(dst + i) = o;
}

// prep: only what the QKV GEMM (launch 2) depends on, plus rope/anymask.
__global__ __launch_bounds__(256) void prep(
    const float* __restrict__ Wqkv, const float* __restrict__ cWqkv,
    const float* __restrict__ x, const float* __restrict__ ctx,
    const int* __restrict__ mask, const int* __restrict__ spos,
    bf16* __restrict__ WqkvT, bf16* __restrict__ cWqkvT,
    bf16* __restrict__ xbf, bf16* __restrict__ cbf,
    float* __restrict__ rope, int* __restrict__ anym) {
  __shared__ bf16 tile[64][65];
  __shared__ int sh;
  int b = blockIdx.x;
  if (b < 768) { transpose_job64(Wqkv, WqkvT, 1024, 3072, b, tile); return; }
  b -= 768;
  if (b < 768) { transpose_job64(cWqkv, cWqkvT, 1024, 3072, b, tile); return; }
  b -= 768;
  if (b < 4096) { convert_job(x, xbf, b); return; }
  b -= 4096;
  if (b < 512) { convert_job(ctx, cbf, b); return; }
  b -= 512;
  if (b < 2048) {
    // rope table: token = b*4 + t/64 (x tokens only), j = t&63, fi = j>>1
    int t = threadIdx.x;
    int tok = b * 4 + (t >> 6);
    int bb = tok >> 11, s = tok & 2047;
    int j = t & 63, fi = j >> 1;
    float ang = (float)(spos[bb] + s) * expf((float)fi * -0.28782313662425572f);
    rope[(size_t)tok * 64 + j] = (j & 1) ? sinf(ang) : cosf(ang);
    return;
  }
  b -= 2048;
  // anymask: any(mask[b][0][:])
  int a = 0;
  size_t base = (size_t)b * L_SEQ * L_SEQ;
  for (int j = threadIdx.x; j < L_SEQ; j += 256) a |= mask[base + j];
  if (threadIdx.x == 0) sh = 0;
  __syncthreads();
  if (a) atomicOr(&sh, 1);
  __syncthreads();
  if (threadIdx.x == 0) anym[b] = sh;
}

// ---------------------------------------------------------------- QKV GEMM
// 8-phase 256^2 schedule (T3+T4+T2+T5). BM=BN=256, BK=64, 8 waves (2Mx4N,
// wave tile 128x64), 128 KiB dbuf LDS, counted vmcnt(6), region-freedom
// issue schedule p0:AY(t+1) p1:B0(t+2) p2:B1(t+2) p3:AX(t+2), XOR LDS
// swizzle (phys slot = logical ^ (row&7)) via pre-swizzled global source +
// swizzled ds_read.  [verified passing @ R8/R9: 85.5 us, 676 TF]
__global__ __launch_bounds__(512, 2) void gemm_qkv8(
    const bf16* __restrict__ A1, const bf16* __restrict__ A2,
    const bf16* __restrict__ B1t, const bf16* __restrict__ B2t,
    const float* __restrict__ bias1, const float* __restrict__ bias2,
    bf16* __restrict__ qs, bf16* __restrict__ ks, bf16* __restrict__ vs,
    int K, int ybound, int rpb1, int soff1, int rpb2, int soff2) {
  __shared__ bf16 As[2][256 * 64];   // 32 KiB per buf
  __shared__ bf16 Bs[2][256 * 64];

  int nwg = gridDim.x * gridDim.y;
  int wg = blockIdx.y * gridDim.x + blockIdx.x;
  int cpx = nwg >> 3;
  wg = (wg & 7) * cpx + (wg >> 3);          // XCD swizzle (nwg % 8 == 0)
  int bx = wg % gridDim.x, by = wg / gridDim.x;
  int n0 = bx * 256;
  const bf16 *Ap, *Bt;
  const float* bias;
  int m0, rpb, soff;
  if (by < ybound) {
    Ap = A1; Bt = B1t; bias = bias1; m0 = by * 256; rpb = rpb1; soff = soff1;
  } else {
    Ap = A2; Bt = B2t; bias = bias2; m0 = (by - ybound) * 256; rpb = rpb2; soff = soff2;
  }

  int t = threadIdx.x, lane = t & 63, w = t >> 6;
  int wr = w >> 2, wc = w & 3;              // wave tile: rows wr*128, cols wc*64
  int l16 = lane & 15, l4 = lane >> 4;

  // staging invariants: chunk = 8 rows x 128 B; lane -> row lr, 16B slot
  // (lane&7); content pre-swizzled: global slot = (lane&7) ^ (lr&7).
  int lr = lane >> 3;
  int lcol = ((lane & 7) ^ lr) << 3;        // lr in 0..7 == lr&7
  const bf16* Ag = Ap + (size_t)(m0 + lr) * K + lcol;
  const bf16* Bg = Bt + (size_t)(n0 + lr) * K + lcol;

  // per-wave chunk bases (2 consecutive chunks each)
  int cB0 = w * 2;                          // B rows 0-127
  int cB1 = 16 + w * 2;                     // B rows 128-255
  int cAX = ((w & 4) << 2) + (w & 3) * 2;   // A rows {0-63, 128-191}
  int cAY = 8 + cAX;                        // A rows {64-127, 192-255}

  auto stg = [&](const bf16* G, bf16* Ldst, int c0, int kb) {
#pragma unroll
    for (int j = 0; j < 2; j++) {
      int c = c0 + j;
      gload_lds16(G + (size_t)(c * 8) * K + kb, (char*)Ldst + c * 1024);
    }
  };
  // swizzled ds_read of fragment: logical slot = ks*4 + l4, row base mult 16
  auto ldf = [&](const bf16* S, int row, int ks) {
    return *(const bf16x8*)&S[row * 64 + ((((ks << 2) + l4) ^ (l16 & 7)) << 3)];
  };

  floatx4 acc[8][4] = {};
  int NT = K >> 6;
  // prologue: tile 0 complete + tile 1 all but A-halfY (issued at tt=0 p0)
  stg(Bg, Bs[0], cB0, 0);  stg(Bg, Bs[0], cB1, 0);
  stg(Ag, As[0], cAX, 0);  stg(Ag, As[0], cAY, 0);
  if (NT > 1) {
    stg(Bg, Bs[1], cB0, 64); stg(Bg, Bs[1], cB1, 64);
    stg(Ag, As[1], cAX, 64);
  }
  asm volatile("s_waitcnt vmcnt(6)" ::: "memory");   // tile 0 landed
  __builtin_amdgcn_s_barrier();

  int pb = 0;
  bf16x8 bfr[4][2];
  for (int tt = 0; tt < NT; ++tt) {
    int kb = tt << 6;
    const bf16* Asp = As[pb];
    const bf16* Bsp = Bs[pb];
#pragma unroll
    for (int p = 0; p < 4; ++p) {
      if (p == 0) {
#pragma unroll
        for (int nt = 0; nt < 4; nt++) {
          bfr[nt][0] = ldf(Bsp, wc * 64 + nt * 16 + l16, 0);
          bfr[nt][1] = ldf(Bsp, wc * 64 + nt * 16 + l16, 1);
        }
      }
      int ar = wr * 128 + p * 32 + l16;
      bf16x8 a00 = ldf(Asp, ar, 0);
      bf16x8 a01 = ldf(Asp, ar, 1);
      bf16x8 a10 = ldf(Asp, ar + 16, 0);
      bf16x8 a11 = ldf(Asp, ar + 16, 1);
      // prefetch issue (regions freed per ledger above)
      if (p == 0)      { if (tt + 1 < NT) stg(Ag, As[pb ^ 1], cAY, kb + 64); }
      else if (p == 1) { if (tt + 2 < NT) stg(Bg, Bs[pb], cB0, kb + 128); }
      else if (p == 2) { if (tt + 2 < NT) stg(Bg, Bs[pb], cB1, kb + 128); }
      else             { if (tt + 2 < NT) stg(Ag, As[pb], cAX, kb + 128); }
      __builtin_amdgcn_s_barrier();
      __builtin_amdgcn_s_setprio(1);
      int mt = p * 2;
#pragma unroll
      for (int nt = 0; nt < 4; nt++) {
        acc[mt][nt]     = __builtin_amdgcn_mfma_f32_16x16x32_bf16(a00, bfr[nt][0], acc[mt][nt], 0, 0, 0);
        acc[mt][nt]     = __builtin_amdgcn_mfma_f32_16x16x32_bf16(a01, bfr[nt][1], acc[mt][nt], 0, 0, 0);
        acc[mt + 1][nt] = __builtin_amdgcn_mfma_f32_16x16x32_bf16(a10, bfr[nt][0], acc[mt + 1][nt], 0, 0, 0);
        acc[mt + 1][nt] = __builtin_amdgcn_mfma_f32_16x16x32_bf16(a11, bfr[nt][1], acc[mt + 1][nt], 0, 0, 0);
      }
      __builtin_amdgcn_s_setprio(0);
      if (p == 3) {                      // tile boundary: counted drain
        if (tt + 2 < NT) asm volatile("s_waitcnt vmcnt(6)" ::: "memory");
        else             asm volatile("s_waitcnt vmcnt(0)" ::: "memory");
      }
      __builtin_amdgcn_s_barrier();
    }
    pb ^= 1;
  }

  // epilogue: scatter; D[row=(l>>4)*4+r][col=l&15] per 16x16 tile
#pragma unroll
  for (int mt = 0; mt < 8; mt++)
#pragma unroll
    for (int nt = 0; nt < 4; nt++) {
      int col = n0 + wc * 64 + nt * 16 + l16;
      float bval = bias[col];
      int which = col >> 10;
      int h = (col >> 6) & 15;
      int dh = col & 63;
      int rmask = (1 << rpb) - 1;
      if (which == 2) {
        int rw0 = m0 + wr * 128 + mt * 16 + l4 * 4;
        int b = rw0 >> rpb;
        int s = soff + (rw0 & rmask);
        bf16x4 o;
#pragma unroll
        for (int r = 0; r < 4; r++) o[r] = (bf16)(acc[mt][nt][r] + bval);
        *(bf16x4*)(vs + ((size_t)(b * NHEAD + h) * DHEAD + dh) * S_SEQ + s) = o;
      } else {
        bf16* dst = which == 0 ? qs : ks;
#pragma unroll
        for (int r = 0; r < 4; r++) {
          int rw = m0 + wr * 128 + mt * 16 + l4 * 4 + r;
          int b = rw >> rpb;
          int s = soff + (rw & rmask);
          dst[((size_t)(b * NHEAD + h) * S_SEQ + s) * DHEAD + dh] =
              (bf16)(acc[mt][nt][r] + bval);
        }
      }
    }
}

// ---------------------------------------------------------------- out GEMM
// PROVEN R5 config: 128x128 tile, BK=32, 4 waves, 2-phase dbuf, rotation
// bank swizzle, ~3 blocks/CU. (See R5 notes; m132 precedent says BK=64's
// occupancy trade loses here.)
template <bool SCATTER>
__global__ __launch_bounds__(256) void gemm_bias(
    const bf16* __restrict__ A1, const bf16* __restrict__ A2,
    const bf16* __restrict__ B1t, const bf16* __restrict__ B2t,
    const float* __restrict__ bias1, const float* __restrict__ bias2,
    bf16* __restrict__ C1, bf16* __restrict__ C2,
    bf16* __restrict__ qs, bf16* __restrict__ ks, bf16* __restrict__ vs,
    int N, int K, int ybound,
    int rpb1, int soff1, int rpb2, int soff2) {
  __shared__ bf16 As[2][4096];
  __shared__ bf16 Bs[2][4096];
  int nwg = gridDim.x * gridDim.y;
  int wg = blockIdx.y * gridDim.x + blockIdx.x;
  int cpx = nwg >> 3;
  wg = (wg & 7) * cpx + (wg >> 3);
  int bx = wg % gridDim.x, by = wg / gridDim.x;
  int n0 = bx * 128;
  const bf16 *Ap, *Bt;
  const float* bias;
  bf16* Cp;
  int m0, rpb, soff;
  if (by < ybound) {
    Ap = A1; Bt = B1t; bias = bias1; Cp = C1;
    m0 = by * 128; rpb = rpb1; soff = soff1;
  } else {
    Ap = A2; Bt = B2t; bias = bias2; Cp = C2;
    m0 = (by - ybound) * 128; rpb = rpb2; soff = soff2;
  }
  int t = threadIdx.x, lane = t & 63, w = t >> 6;
  int wm = (w & 1) * 64, wn = (w >> 1) * 64;
  int l16 = lane & 15, l4 = lane >> 4;
  int crow = w * 32 + (lane >> 2);
  int scol = ((((lane & 3) - ((lane >> 3) & 3)) & 3)) << 3;
  const bf16* Ab = Ap + (size_t)(m0 + crow) * K + scol;
  const bf16* Bb = Bt + (size_t)(n0 + crow) * K + scol;
  auto stage = [&](int buf, int kb) {
#pragma unroll
    for (int j = 0; j < 2; j++) {
      gload_lds16(Ab + (size_t)(j * 16) * K + kb, (char*)As[buf] + (w * 2 + j) * 1024);
      gload_lds16(Bb + (size_t)(j * 16) * K + kb, (char*)Bs[buf] + (w * 2 + j) * 1024);
    }
  };
  int co = ((l4 + ((l16 >> 1) & 3)) & 3) << 3;
  int rba = (wm + l16) * 32 + co;
  int rbb = (wn + l16) * 32 + co;
  floatx4 acc[4][4] = {};
  stage(0, 0);
  __syncthreads();
  int NTt = K >> 5;
  for (int tt = 0; tt < NTt; ++tt) {
    int p = tt & 1;
    if (tt + 1 < NTt) stage(p ^ 1, (tt + 1) << 5);
    bf16x8 bfr[4];
#pragma unroll
    for (int nt = 0; nt < 4; nt++) bfr[nt] = *(const bf16x8*)&Bs[p][rbb + nt * 512];
    __builtin_amdgcn_s_setprio(1);
#pragma unroll
    for (int mt = 0; mt < 4; mt++) {
      bf16x8 a = *(const bf16x8*)&As[p][rba + mt * 512];
#pragma unroll
      for (int nt = 0; nt < 4; nt++)
        acc[mt][nt] = __builtin_amdgcn_mfma_f32_16x16x32_bf16(a, bfr[nt], acc[mt][nt], 0, 0, 0);
    }
    __builtin_amdgcn_s_setprio(0);
    __syncthreads();
  }
#pragma unroll
  for (int mt = 0; mt < 4; mt++)
#pragma unroll
    for (int nt = 0; nt < 4; nt++) {
      int col = n0 + wn + nt * 16 + l16;
      float bval = bias[col];
      if constexpr (SCATTER) {
        int which = col >> 10;
        int h = (col >> 6) & 15;
        int dh = col & 63;
        int rmask = (1 << rpb) - 1;
        if (which == 2) {
          int rw0 = m0 + wm + mt * 16 + l4 * 4;
          int b = rw0 >> rpb;
          int s = soff + (rw0 & rmask);
          bf16x4 o;
#pragma unroll
          for (int r = 0; r < 4; r++) o[r] = (bf16)(acc[mt][nt][r] + bval);
          *(bf16x4*)(vs + ((size_t)(b * NHEAD + h) * DHEAD + dh) * S_SEQ + s) = o;
        } else {
          bf16* dst = which == 0 ? qs : ks;
#pragma unroll
          for (int r = 0; r < 4; r++) {
            int rw = m0 + wm + mt * 16 + l4 * 4 + r;
            int b = rw >> rpb;
            int s = soff + (rw & rmask);
            dst[((size_t)(b * NHEAD + h) * S_SEQ + s) * DHEAD + dh] =
                (bf16)(acc[mt][nt][r] + bval);
          }
        }
      } else {
#pragma unroll
        for (int r = 0; r < 4; r++) {
          int rw = m0 + wm + mt * 16 + l4 * 4 + r;
          Cp[(size_t)rw * N + col] = (bf16)(acc[mt][nt][r] + bval);
        }
      }
    }
}

// ---------------------------------------------------------------- qkv post
// 2 tokens per block, 128 threads/token, 16 B/lane. Extra block ranges
// absorb work only needed by LATER launches.
__global__ __launch_bounds__(256) void qkv_post(
    bf16* __restrict__ qs, bf16* __restrict__ ks,
    const int* __restrict__ mask, const float* __restrict__ rope,
    const int* __restrict__ anym,
    const float* __restrict__ g_q, const float* __restrict__ g_k,
    const float* __restrict__ cg_q, const float* __restrict__ cg_k,
    const float* __restrict__ Wout, const float* __restrict__ cWout,
    bf16* __restrict__ WoutT, bf16* __restrict__ cWoutT,
    float* __restrict__ vkw) {
  __shared__ bf16 tile[64][65];
  __shared__ float red[8];
  int blk = blockIdx.x, t = threadIdx.x;
  if (blk >= 4608) {
    int b = blk - 4608;
    if (b < 256) { transpose_job64(Wout, WoutT, 1024, 1024, b, tile); return; }
    b -= 256;
    if (b < 256) { transpose_job64(cWout, cWoutT, 1024, 1024, b, tile); return; }
    b -= 256;
    int i = b * 1024 + t * 4;
    *(floatx4*)(vkw + i) = floatx4{0.f, 0.f, 0.f, 0.f};
    return;
  }
  int tt = t & 127, tsel = t >> 7;
  int g = blk * 2 + tsel;                       // token id (x: <8192, ctx rest)
  bool is_ctx = g >= NBATCH * L_SEQ;
  int b, s;
  const float *gq, *gk;
  float mval;
  if (!is_ctx) {
    b = g >> 11;
    int l = g & 2047;
    s = l;
    mval = mask[(size_t)b * L_SEQ * L_SEQ + l] ? 1.f : 0.f;  // mask[b][0][l]
    gq = g_q; gk = g_k;
  } else {
    int gg = g - NBATCH * L_SEQ;
    b = gg >> 8;
    s = L_SEQ + (gg & 255);
    mval = anym[b] ? 1.f : 0.f;
    gq = cg_q; gk = cg_k;
  }
  int d0 = tt * 8;
  int h = tt >> 3, dh = (tt & 7) * 8;           // h*64+dh == d0
  size_t base = ((size_t)(b * NHEAD + h) * S_SEQ + s) * DHEAD + dh;
  bf16x8 q8 = *(const bf16x8*)(qs + base);
  bf16x8 k8 = *(const bf16x8*)(ks + base);
  float qv[8], kv[8], pq = 0.f, pk = 0.f;
#pragma unroll
  for (int i = 0; i < 8; i++) {
    qv[i] = (float)q8[i]; kv[i] = (float)k8[i];
    pq += qv[i] * qv[i];  pk += kv[i] * kv[i];
  }
  int w = t >> 6;                                // wave id 0..3
  for (int off = 32; off > 0; off >>= 1) {
    pq += __shfl_down(pq, off, 64);
    pk += __shfl_down(pk, off, 64);
  }
  if ((t & 63) == 0) { red[w] = pq; red[4 + w] = pk; }
  __syncthreads();
  float sq = red[tsel * 2] + red[tsel * 2 + 1];
  float sk = red[4 + tsel * 2] + red[4 + tsel * 2 + 1];
  float scq = rsqrtf(sq * (1.f / DMODEL) + RMS_EPS);
  float sck = rsqrtf(sk * (1.f / DMODEL) + RMS_EPS);
#pragma unroll
  for (int i = 0; i < 8; i++) {
    qv[i] *= scq * gq[d0 + i];
    kv[i] *= sck * gk[d0 + i];
  }
  if (!is_ctx) {
    // table: 64 entries PER TOKEN indexed by HEAD dim dh (cos even, sin odd)
    floatx4 ta = *(const floatx4*)&rope[((size_t)g) * 64 + dh];
    floatx4 tb = *(const floatx4*)&rope[((size_t)g) * 64 + dh + 4];
#pragma unroll
    for (int pr = 0; pr < 4; pr++) {
      float cc = pr < 2 ? ta[2 * pr] : tb[2 * (pr - 2)];
      float ss = pr < 2 ? ta[2 * pr + 1] : tb[2 * (pr - 2) + 1];
      float t0 = qv[2 * pr], t1 = qv[2 * pr + 1];
      qv[2 * pr]     = t0 * cc - t1 * ss;
      qv[2 * pr + 1] = t0 * ss + t1 * cc;
      t0 = kv[2 * pr]; t1 = kv[2 * pr + 1];
      kv[2 * pr]     = t0 * cc - t1 * ss;
      kv[2 * pr + 1] = t0 * ss + t1 * cc;
    }
  }
  bf16x8 qo, ko;
#pragma unroll
  for (int i = 0; i < 8; i++) {
    qo[i] = (bf16)fmaxf(qv[i], 0.f);
    ko[i] = (bf16)(fmaxf(kv[i], 0.f) * mval);
  }
  *(bf16x8*)(qs + base) = qo;
  *(bf16x8*)(ks + base) = ko;
}

// ---------------------------------------------------------------- vk (MFMA)
#define VK_CH   12
#define VK_SPAN (S_SEQ / VK_CH)   // 192 = 6 K-steps of 32
__global__ __launch_bounds__(256) void vk_mfma(
    const bf16* __restrict__ vT, const bf16* __restrict__ kf,
    float* __restrict__ vk) {
  __shared__ bf16 Vs[2][64][40];
  __shared__ bf16 Ks[2][64][40];   // Ks[d][s]
  int bh = blockIdx.x / VK_CH, chunk = blockIdx.x % VK_CH;
  int t = threadIdx.x, lane = t & 63, w = t >> 6;
  int l16 = lane & 15, l4 = lane >> 4;
  const bf16* vp = vT + (size_t)bh * DHEAD * S_SEQ;
  const bf16* kp = kf + (size_t)bh * S_SEQ * DHEAD;
  int s_begin = chunk * VK_SPAN;
  int ve = t >> 2, vso = (t & 3) * 8;        // v staging: row e, col offset
  int ks_s = t & 31, kd0 = (t >> 5) * 8;     // kf staging: s-slice, d-octet
  floatx4 acc[4] = {};
  float dsum[8] = {};
  bf16x8 vv = *(const bf16x8*)(vp + (size_t)ve * S_SEQ + s_begin + vso);
  bf16x8 kv = *(const bf16x8*)(kp + (size_t)(s_begin + ks_s) * DHEAD + kd0);
  for (int st = 0; st < VK_SPAN; st += 32) {
    int cur = (st >> 5) & 1;
    *(bf16x8*)&Vs[cur][ve][vso] = vv;
#pragma unroll
    for (int j = 0; j < 8; j++) {
      Ks[cur][kd0 + j][ks_s] = kv[j];
      dsum[j] += (float)kv[j];
    }
    if (st + 32 < VK_SPAN) {
      int s0 = s_begin + st + 32;
      vv = *(const bf16x8*)(vp + (size_t)ve * S_SEQ + s0 + vso);
      kv = *(const bf16x8*)(kp + (size_t)(s0 + ks_s) * DHEAD + kd0);
    }
    __syncthreads();
    bf16x8 af = *(const bf16x8*)&Vs[cur][w * 16 + l16][l4 * 8];
#pragma unroll
    for (int nt = 0; nt < 4; nt++) {
      bf16x8 bfr = *(const bf16x8*)&Ks[cur][nt * 16 + l16][l4 * 8];
      acc[nt] = __builtin_amdgcn_mfma_f32_16x16x32_bf16(af, bfr, acc[nt], 0, 0, 0);
    }
  }
  float* vkbh = vk + (size_t)bh * 65 * 64;
#pragma unroll
  for (int nt = 0; nt < 4; nt++)
#pragma unroll
    for (int r = 0; r < 4; r++)
      atomicAdd(&vkbh[(w * 16 + l4 * 4 + r) * 64 + nt * 16 + l16], acc[nt][r]);
#pragma unroll
  for (int j = 0; j < 8; j++)
#pragma unroll
    for (int off = 16; off > 0; off >>= 1)
      dsum[j] += __shfl_down(dsum[j], off, 32);
  if ((lane & 31) == 0)
#pragma unroll
    for (int j = 0; j < 8; j++)
      atomicAdd(&vkbh[64 * 64 + kd0 + j], dsum[j]);
}

// ---------------------------------------------------------------- res + div
__global__ __launch_bounds__(256) void res_attn(
    const bf16* __restrict__ qf, const float* __restrict__ vk,
    bf16* __restrict__ attn_x, bf16* __restrict__ attn_c) {
  __shared__ bf16 Bs[80][72];
  __shared__ float sden[256];
  int bh = blockIdx.x / 9, mblk = blockIdx.x % 9;
  int b = bh >> 4, h = bh & 15;
  int t = threadIdx.x, lane = t & 63, w = t >> 6;
  const float* vkp = vk + (size_t)bh * 65 * 64;
  for (int i = t; i < 80 * 64; i += 256) {
    int e = i >> 6, d = i & 63;
    Bs[e][d] = (bf16)(e < 65 ? vkp[i] : 0.f);
  }
  __syncthreads();
  int l16 = lane & 15, l4 = lane >> 4;
  const bf16* qbase = qf + (size_t)bh * S_SEQ * DHEAD;
  int q0w = mblk * 256 + w * 64;

  floatx4 acc[4][5] = {};
  bf16x8 af[4][2], bfr[5][2];
#pragma unroll
  for (int mt = 0; mt < 4; mt++) {
    int q = q0w + mt * 16 + l16;
    af[mt][0] = *(const bf16x8*)(qbase + (size_t)q * 64 + l4 * 8);
    af[mt][1] = *(const bf16x8*)(qbase + (size_t)q * 64 + 32 + l4 * 8);
  }
#pragma unroll
  for (int nt = 0; nt < 5; nt++) {
    bfr[nt][0] = *(const bf16x8*)&Bs[nt * 16 + l16][l4 * 8];
    bfr[nt][1] = *(const bf16x8*)&Bs[nt * 16 + l16][32 + l4 * 8];
  }
#pragma unroll
  for (int mt = 0; mt < 4; mt++)
#pragma unroll
    for (int nt = 0; nt < 5; nt++) {
      acc[mt][nt] = __builtin_amdgcn_mfma_f32_16x16x32_bf16(af[mt][0], bfr[nt][0], acc[mt][nt], 0, 0, 0);
      acc[mt][nt] = __builtin_amdgcn_mfma_f32_16x16x32_bf16(af[mt][1], bfr[nt][1], acc[mt][nt], 0, 0, 0);
    }
  // denominator: e=64 = col 0 of n-tile 4 (lanes with l16==0)
  if (l16 == 0) {
#pragma unroll
    for (int mt = 0; mt < 4; mt++)
#pragma unroll
      for (int r = 0; r < 4; r++)
        sden[w * 64 + mt * 16 + l4 * 4 + r] = acc[mt][4][r];
  }
  __syncthreads();
#pragma unroll
  for (int mt = 0; mt < 4; mt++)
#pragma unroll
    for (int r = 0; r < 4; r++) {
      float den = sden[w * 64 + mt * 16 + l4 * 4 + r] + LIN_EPS;
      float rden = 1.f / den;
      int q = q0w + mt * 16 + l4 * 4 + r;
#pragma unroll
      for (int nt = 0; nt < 4; nt++) {
        int dcol = nt * 16 + l16;
        float a = acc[mt][nt][r] * rden;
        if (q < L_SEQ)
          attn_x[((size_t)b * L_SEQ + q) * DMODEL + h * DHEAD + dcol] = (bf16)a;
        else
          attn_c[((size_t)b * C_SEQ + (q - L_SEQ)) * DMODEL + h * DHEAD + dcol] = (bf16)a;
      }
    }
}

// ---------------------------------------------------------------- final norm
// 2 rows/block, 128 threads/row, 16 B/lane in, 32 B/lane out (f32).
__global__ __launch_bounds__(256) void final_norm(
    const bf16* __restrict__ y_x, const bf16* __restrict__ y_c,
    const float* __restrict__ g_out, const float* __restrict__ cg_out,
    float* __restrict__ out) {
  __shared__ float red[8];
  int t = threadIdx.x;
  int tt = t & 127, tsel = t >> 7;
  int g = blockIdx.x * 2 + tsel;
  const bf16* src;
  const float* gv;
  if (g < NBATCH * L_SEQ) {
    src = y_x + (size_t)g * DMODEL; gv = g_out;
  } else {
    int gg = g - NBATCH * L_SEQ;
    src = y_c + (size_t)gg * DMODEL; gv = cg_out;
  }
  float* dst = out + (size_t)g * DMODEL;
  int d0 = tt * 8;
  bf16x8 y8 = *(const bf16x8*)(src + d0);
  float yv[8], p = 0.f;
#pragma unroll
  for (int i = 0; i < 8; i++) { yv[i] = (float)y8[i]; p += yv[i] * yv[i]; }
  int w = t >> 6;
  for (int off = 32; off > 0; off >>= 1) p += __shfl_down(p, off, 64);
  if ((t & 63) == 0) red[w] = p;
  __syncthreads();
  float ssum = red[tsel * 2] + red[tsel * 2 + 1];
  float sc = rsqrtf(ssum * (1.f / DMODEL) + RMS_EPS);
  floatx4 o0, o1;
#pragma unroll
  for (int i = 0; i < 4; i++) {
    o0[i] = yv[i] * sc * gv[d0 + i];
    o1[i] = yv[4 + i] * sc * gv[d0 + 4 + i];
  }
  *(floatx4*)(dst + d0) = o0;
  *(floatx4*)(dst + d0 + 4) = o1;
}

// ---------------------------------------------------------------- launch
extern "C" void kernel_launch(void* const* d_in, const int* in_sizes, int n_in,
                              void* d_out, int out_size, void* d_ws, size_t ws_size,
                              hipStream_t stream) {
  const float* x      = (const float*)d_in[0];
  const float* ctx    = (const float*)d_in[1];
  const int*   mask   = (const int*)d_in[2];
  const int*   spos   = (const int*)d_in[3];
  const float* Wqkv   = (const float*)d_in[4];
  const float* bqkv   = (const float*)d_in[5];
  const float* g_q    = (const float*)d_in[6];
  const float* g_k    = (const float*)d_in[7];
  const float* cWqkv  = (const float*)d_in[8];
  const float* cbqkv  = (const float*)d_in[9];
  const float* cg_q   = (const float*)d_in[10];
  const float* cg_k   = (const float*)d_in[11];
  const float* Wout   = (const float*)d_in[12];
  const float* bout   = (const float*)d_in[13];
  const float* g_out  = (const float*)d_in[14];
  const float* cWout  = (const float*)d_in[15];
  const float* cbout  = (const float*)d_in[16];
  const float* cg_out = (const float*)d_in[17];

  char* wsp = (char*)d_ws;
  size_t off = 0;
  auto alloc = [&](size_t bytes) -> void* {
    void* p = wsp + off;
    off += (bytes + 255) & ~(size_t)255;
    return p;
  };
  bf16* WqkvT  = (bf16*)alloc((size_t)3072 * 1024 * 2);
  bf16* cWqkvT = (bf16*)alloc((size_t)3072 * 1024 * 2);
  bf16* WoutT  = (bf16*)alloc((size_t)1024 * 1024 * 2);
  bf16* cWoutT = (bf16*)alloc((size_t)1024 * 1024 * 2);
  bf16* xbf    = (bf16*)alloc((size_t)NBATCH * L_SEQ * DMODEL * 2);
  bf16* cbf    = (bf16*)alloc((size_t)NBATCH * C_SEQ * DMODEL * 2);
  const size_t SLAB = (size_t)NBATCH * NHEAD * S_SEQ * DHEAD;  // 9,437,184
  bf16* qfs    = (bf16*)alloc(SLAB * 2);
  bf16* kfs    = (bf16*)alloc(SLAB * 2);
  bf16* vfs    = (bf16*)alloc(SLAB * 2);   // holds vT [bh][d][s]
  float* vkw   = (float*)alloc((size_t)64 * 65 * 64 * 4);
  float* rope  = (float*)alloc((size_t)NBATCH * L_SEQ * 64 * 4);
  int* anym    = (int*)alloc(256);
  // attn aliases kf slab (dead after vk_mfma); y aliases v slab.
  bf16* attn_x = kfs;
  bf16* attn_c = kfs + (size_t)NBATCH * L_SEQ * DMODEL;
  bf16* y_x    = vfs;
  bf16* y_c    = vfs + (size_t)NBATCH * L_SEQ * DMODEL;

  // 1) prep (QKV-critical only): Wqkv/cWqkv transposes, converts, rope, anymask
  prep<<<8196, 256, 0, stream>>>(Wqkv, cWqkv, x, ctx, mask, spos,
                                 WqkvT, cWqkvT, xbf, cbf, rope, anym);

  // 2) QKV projections (x + ctx in one launch): 8-phase 256^2 schedule
  gemm_qkv8<<<dim3(12, 36), 512, 0, stream>>>(
      xbf, cbf, WqkvT, cWqkvT, bqkv, cbqkv,
      qfs, kfs, vfs, 1024, 32, 11, 0, 8, L_SEQ);

  // 3) qkv post (16 B/lane) + deferred Wout/cWout transposes + vkw zero
  qkv_post<<<5380, 256, 0, stream>>>(
      qfs, kfs, mask, rope, anym, g_q, g_k, cg_q, cg_k,
      Wout, cWout, WoutT, cWoutT, vkw);

  // 4) vk = vT kf via MFMA
  vk_mfma<<<64 * VK_CH, 256, 0, stream>>>(vfs, kfs, vkw);

  // 5) res = qf vk^T, divide, scatter to token-major (B,S,D)
  res_attn<<<576, 256, 0, stream>>>(qfs, vkw, attn_x, attn_c);

  // 6) output projections (x + ctx in one launch), proven 128^2 2-phase
  gemm_bias<false><<<dim3(8, 72), 256, 0, stream>>>(
      attn_x, attn_c, WoutT, cWoutT, bout, cbout, y_x, y_c,
      nullptr, nullptr, nullptr, 1024, 1024, 64, 0, 0, 0, 0);

  // 7) final rmsnorm -> FLOAT32 d_out (x_out rows then c_out rows)
  final_norm<<<4608, 256, 0, stream>>>(
      y_x, y_c, g_out, cg_out, (float*)d_out);
}

// Round 13
// 342.682 us; speedup vs baseline: 1.0224x; 1.0057x over previous
//
#include <hip/hip_runtime.h>

typedef __bf16 bf16;
typedef __bf16 bf16x4 __attribute__((ext_vector_type(4)));
typedef __bf16 bf16x8 __attribute__((ext_vector_type(8)));
typedef float  floatx4 __attribute__((ext_vector_type(4)));

#define L_SEQ   2048
#define C_SEQ   256
#define S_SEQ   2304
#define NBATCH  4
#define NHEAD   16
#define DHEAD   64
#define DMODEL  1024
#define RMS_EPS 1.1920928955078125e-07f
#define LIN_EPS 1e-6f

// async global->LDS, 16B per lane; LDS dest must be wave-uniform (+lane*16)
__device__ __forceinline__ void gload_lds16(const void* g, void* l) {
  __builtin_amdgcn_global_load_lds(
      (const __attribute__((address_space(1))) void*)g,
      (__attribute__((address_space(3))) void*)l, 16, 0, 0);
}

// ---------------------------------------------------------------- prep jobs
// 64x64 transpose tile: float4 reads, LDS stored transposed, bf16x4 writes
// (128 B contiguous dst segments).
__device__ __forceinline__ void transpose_job64(
    const float* __restrict__ src, bf16* __restrict__ dst,
    int R, int C, int tb, bf16 (*tile)[65]) {
  int tilesx = C >> 6;
  int c0 = (tb % tilesx) * 64, r0 = (tb / tilesx) * 64;
  int tx = threadIdx.x & 15, ty = threadIdx.x >> 4;   // 16 cols x 16 rows
#pragma unroll
  for (int it = 0; it < 4; it++) {
    int rl = ty + it * 16;
    floatx4 v = *(const floatx4*)(src + (size_t)(r0 + rl) * C + c0 + tx * 4);
#pragma unroll
    for (int j = 0; j < 4; j++) tile[tx * 4 + j][rl] = (bf16)v[j];  // [col][row]
  }
  __syncthreads();
#pragma unroll
  for (int it = 0; it < 4; it++) {
    int i = ty + it * 16;                              // dst row = src col
    bf16x4 o = *(const bf16x4*)&tile[i][tx * 4];
    *(bf16x4*)(dst + (size_t)(c0 + i) * R + r0 + tx * 4) = o;
  }
}

__device__ __forceinline__ void convert_job(
    const float* __restrict__ src, bf16* __restrict__ dst, int tb) {
  size_t i = ((size_t)tb * 256 + threadIdx.x) * 8;
  floatx4 a = *(const floatx4*)(src + i);
  floatx4 b = *(const floatx4*)(src + i + 4);
  bf16x8 o;
#pragma unroll
  for (int j = 0; j < 4; j++) { o[j] = (bf16)a[j]; o[4 + j] = (bf16)b[j]; }
  *(bf16x8*)(dst + i) = o;
}

// prep: only what the QKV GEMM (launch 2) depends on, plus rope/anymask.
__global__ __launch_bounds__(256) void prep(
    const float* __restrict__ Wqkv, const float* __restrict__ cWqkv,
    const float* __restrict__ x, const float* __restrict__ ctx,
    const int* __restrict__ mask, const int* __restrict__ spos,
    bf16* __restrict__ WqkvT, bf16* __restrict__ cWqkvT,
    bf16* __restrict__ xbf, bf16* __restrict__ cbf,
    float* __restrict__ rope, int* __restrict__ anym) {
  __shared__ bf16 tile[64][65];
  __shared__ int sh;
  int b = blockIdx.x;
  if (b < 768) { transpose_job64(Wqkv, WqkvT, 1024, 3072, b, tile); return; }
  b -= 768;
  if (b < 768) { transpose_job64(cWqkv, cWqkvT, 1024, 3072, b, tile); return; }
  b -= 768;
  if (b < 4096) { convert_job(x, xbf, b); return; }
  b -= 4096;
  if (b < 512) { convert_job(ctx, cbf, b); return; }
  b -= 512;
  if (b < 2048) {
    // rope table: token = b*4 + t/64 (x tokens only), j = t&63, fi = j>>1
    int t = threadIdx.x;
    int tok = b * 4 + (t >> 6);
    int bb = tok >> 11, s = tok & 2047;
    int j = t & 63, fi = j >> 1;
    float ang = (float)(spos[bb] + s) * expf((float)fi * -0.28782313662425572f);
    rope[(size_t)tok * 64 + j] = (j & 1) ? sinf(ang) : cosf(ang);
    return;
  }
  b -= 2048;
  // anymask: any(mask[b][0][:])
  int a = 0;
  size_t base = (size_t)b * L_SEQ * L_SEQ;
  for (int j = threadIdx.x; j < L_SEQ; j += 256) a |= mask[base + j];
  if (threadIdx.x == 0) sh = 0;
  __syncthreads();
  if (a) atomicOr(&sh, 1);
  __syncthreads();
  if (threadIdx.x == 0) anym[b] = sh;
}

// ---------------------------------------------------------------- QKV GEMM
// 8-phase 256^2 schedule (T3+T4+T2+T5). BM=BN=256, BK=64, 8 waves (2Mx4N,
// wave tile 128x64), 128 KiB dbuf LDS, counted vmcnt(6), region-freedom
// issue schedule p0:AY(t+1) p1:B0(t+2) p2:B1(t+2) p3:AX(t+2), XOR LDS
// swizzle (phys slot = logical ^ (row&7)) via pre-swizzled global source +
// swizzled ds_read.  [verified passing @ R8/R9/R11: ~84.5 us, 680 TF]
__global__ __launch_bounds__(512, 2) void gemm_qkv8(
    const bf16* __restrict__ A1, const bf16* __restrict__ A2,
    const bf16* __restrict__ B1t, const bf16* __restrict__ B2t,
    const float* __restrict__ bias1, const float* __restrict__ bias2,
    bf16* __restrict__ qs, bf16* __restrict__ ks, bf16* __restrict__ vs,
    int K, int ybound, int rpb1, int soff1, int rpb2, int soff2) {
  __shared__ bf16 As[2][256 * 64];   // 32 KiB per buf
  __shared__ bf16 Bs[2][256 * 64];

  int nwg = gridDim.x * gridDim.y;
  int wg = blockIdx.y * gridDim.x + blockIdx.x;
  int cpx = nwg >> 3;
  wg = (wg & 7) * cpx + (wg >> 3);          // XCD swizzle (nwg % 8 == 0)
  int bx = wg % gridDim.x, by = wg / gridDim.x;
  int n0 = bx * 256;
  const bf16 *Ap, *Bt;
  const float* bias;
  int m0, rpb, soff;
  if (by < ybound) {
    Ap = A1; Bt = B1t; bias = bias1; m0 = by * 256; rpb = rpb1; soff = soff1;
  } else {
    Ap = A2; Bt = B2t; bias = bias2; m0 = (by - ybound) * 256; rpb = rpb2; soff = soff2;
  }

  int t = threadIdx.x, lane = t & 63, w = t >> 6;
  int wr = w >> 2, wc = w & 3;              // wave tile: rows wr*128, cols wc*64
  int l16 = lane & 15, l4 = lane >> 4;

  // staging invariants: chunk = 8 rows x 128 B; lane -> row lr, 16B slot
  // (lane&7); content pre-swizzled: global slot = (lane&7) ^ (lr&7).
  int lr = lane >> 3;
  int lcol = ((lane & 7) ^ lr) << 3;        // lr in 0..7 == lr&7
  const bf16* Ag = Ap + (size_t)(m0 + lr) * K + lcol;
  const bf16* Bg = Bt + (size_t)(n0 + lr) * K + lcol;

  // per-wave chunk bases (2 consecutive chunks each)
  int cB0 = w * 2;                          // B rows 0-127
  int cB1 = 16 + w * 2;                     // B rows 128-255
  int cAX = ((w & 4) << 2) + (w & 3) * 2;   // A rows {0-63, 128-191}
  int cAY = 8 + cAX;                        // A rows {64-127, 192-255}

  auto stg = [&](const bf16* G, bf16* Ldst, int c0, int kb) {
#pragma unroll
    for (int j = 0; j < 2; j++) {
      int c = c0 + j;
      gload_lds16(G + (size_t)(c * 8) * K + kb, (char*)Ldst + c * 1024);
    }
  };
  // swizzled ds_read of fragment: logical slot = ks*4 + l4, row base mult 16
  auto ldf = [&](const bf16* S, int row, int ks) {
    return *(const bf16x8*)&S[row * 64 + ((((ks << 2) + l4) ^ (l16 & 7)) << 3)];
  };

  floatx4 acc[8][4] = {};
  int NT = K >> 6;
  // prologue: tile 0 complete + tile 1 all but A-halfY (issued at tt=0 p0)
  stg(Bg, Bs[0], cB0, 0);  stg(Bg, Bs[0], cB1, 0);
  stg(Ag, As[0], cAX, 0);  stg(Ag, As[0], cAY, 0);
  if (NT > 1) {
    stg(Bg, Bs[1], cB0, 64); stg(Bg, Bs[1], cB1, 64);
    stg(Ag, As[1], cAX, 64);
  }
  asm volatile("s_waitcnt vmcnt(6)" ::: "memory");   // tile 0 landed
  __builtin_amdgcn_s_barrier();

  int pb = 0;
  bf16x8 bfr[4][2];
  for (int tt = 0; tt < NT; ++tt) {
    int kb = tt << 6;
    const bf16* Asp = As[pb];
    const bf16* Bsp = Bs[pb];
#pragma unroll
    for (int p = 0; p < 4; ++p) {
      if (p == 0) {
#pragma unroll
        for (int nt = 0; nt < 4; nt++) {
          bfr[nt][0] = ldf(Bsp, wc * 64 + nt * 16 + l16, 0);
          bfr[nt][1] = ldf(Bsp, wc * 64 + nt * 16 + l16, 1);
        }
      }
      int ar = wr * 128 + p * 32 + l16;
      bf16x8 a00 = ldf(Asp, ar, 0);
      bf16x8 a01 = ldf(Asp, ar, 1);
      bf16x8 a10 = ldf(Asp, ar + 16, 0);
      bf16x8 a11 = ldf(Asp, ar + 16, 1);
      // prefetch issue (regions freed per ledger above)
      if (p == 0)      { if (tt + 1 < NT) stg(Ag, As[pb ^ 1], cAY, kb + 64); }
      else if (p == 1) { if (tt + 2 < NT) stg(Bg, Bs[pb], cB0, kb + 128); }
      else if (p == 2) { if (tt + 2 < NT) stg(Bg, Bs[pb], cB1, kb + 128); }
      else             { if (tt + 2 < NT) stg(Ag, As[pb], cAX, kb + 128); }
      __builtin_amdgcn_s_barrier();
      __builtin_amdgcn_s_setprio(1);
      int mt = p * 2;
#pragma unroll
      for (int nt = 0; nt < 4; nt++) {
        acc[mt][nt]     = __builtin_amdgcn_mfma_f32_16x16x32_bf16(a00, bfr[nt][0], acc[mt][nt], 0, 0, 0);
        acc[mt][nt]     = __builtin_amdgcn_mfma_f32_16x16x32_bf16(a01, bfr[nt][1], acc[mt][nt], 0, 0, 0);
        acc[mt + 1][nt] = __builtin_amdgcn_mfma_f32_16x16x32_bf16(a10, bfr[nt][0], acc[mt + 1][nt], 0, 0, 0);
        acc[mt + 1][nt] = __builtin_amdgcn_mfma_f32_16x16x32_bf16(a11, bfr[nt][1], acc[mt + 1][nt], 0, 0, 0);
      }
      __builtin_amdgcn_s_setprio(0);
      if (p == 3) {                      // tile boundary: counted drain
        if (tt + 2 < NT) asm volatile("s_waitcnt vmcnt(6)" ::: "memory");
        else             asm volatile("s_waitcnt vmcnt(0)" ::: "memory");
      }
      __builtin_amdgcn_s_barrier();
    }
    pb ^= 1;
  }

  // epilogue: scatter; D[row=(l>>4)*4+r][col=l&15] per 16x16 tile
#pragma unroll
  for (int mt = 0; mt < 8; mt++)
#pragma unroll
    for (int nt = 0; nt < 4; nt++) {
      int col = n0 + wc * 64 + nt * 16 + l16;
      float bval = bias[col];
      int which = col >> 10;
      int h = (col >> 6) & 15;
      int dh = col & 63;
      int rmask = (1 << rpb) - 1;
      if (which == 2) {
        int rw0 = m0 + wr * 128 + mt * 16 + l4 * 4;
        int b = rw0 >> rpb;
        int s = soff + (rw0 & rmask);
        bf16x4 o;
#pragma unroll
        for (int r = 0; r < 4; r++) o[r] = (bf16)(acc[mt][nt][r] + bval);
        *(bf16x4*)(vs + ((size_t)(b * NHEAD + h) * DHEAD + dh) * S_SEQ + s) = o;
      } else {
        bf16* dst = which == 0 ? qs : ks;
#pragma unroll
        for (int r = 0; r < 4; r++) {
          int rw = m0 + wr * 128 + mt * 16 + l4 * 4 + r;
          int b = rw >> rpb;
          int s = soff + (rw & rmask);
          dst[((size_t)(b * NHEAD + h) * S_SEQ + s) * DHEAD + dh] =
              (bf16)(acc[mt][nt][r] + bval);
        }
      }
    }
}

// ---------------------------------------------------------------- out GEMM
// PROVEN R5 config: 128x128 tile, BK=32, 4 waves, 2-phase dbuf, rotation
// bank swizzle, ~3 blocks/CU. (See R5 notes.)
template <bool SCATTER>
__global__ __launch_bounds__(256) void gemm_bias(
    const bf16* __restrict__ A1, const bf16* __restrict__ A2,
    const bf16* __restrict__ B1t, const bf16* __restrict__ B2t,
    const float* __restrict__ bias1, const float* __restrict__ bias2,
    bf16* __restrict__ C1, bf16* __restrict__ C2,
    bf16* __restrict__ qs, bf16* __restrict__ ks, bf16* __restrict__ vs,
    int N, int K, int ybound,
    int rpb1, int soff1, int rpb2, int soff2) {
  __shared__ bf16 As[2][4096];
  __shared__ bf16 Bs[2][4096];
  int nwg = gridDim.x * gridDim.y;
  int wg = blockIdx.y * gridDim.x + blockIdx.x;
  int cpx = nwg >> 3;
  wg = (wg & 7) * cpx + (wg >> 3);
  int bx = wg % gridDim.x, by = wg / gridDim.x;
  int n0 = bx * 128;
  const bf16 *Ap, *Bt;
  const float* bias;
  bf16* Cp;
  int m0, rpb, soff;
  if (by < ybound) {
    Ap = A1; Bt = B1t; bias = bias1; Cp = C1;
    m0 = by * 128; rpb = rpb1; soff = soff1;
  } else {
    Ap = A2; Bt = B2t; bias = bias2; Cp = C2;
    m0 = (by - ybound) * 128; rpb = rpb2; soff = soff2;
  }
  int t = threadIdx.x, lane = t & 63, w = t >> 6;
  int wm = (w & 1) * 64, wn = (w >> 1) * 64;
  int l16 = lane & 15, l4 = lane >> 4;
  int crow = w * 32 + (lane >> 2);
  int scol = ((((lane & 3) - ((lane >> 3) & 3)) & 3)) << 3;
  const bf16* Ab = Ap + (size_t)(m0 + crow) * K + scol;
  const bf16* Bb = Bt + (size_t)(n0 + crow) * K + scol;
  auto stage = [&](int buf, int kb) {
#pragma unroll
    for (int j = 0; j < 2; j++) {
      gload_lds16(Ab + (size_t)(j * 16) * K + kb, (char*)As[buf] + (w * 2 + j) * 1024);
      gload_lds16(Bb + (size_t)(j * 16) * K + kb, (char*)Bs[buf] + (w * 2 + j) * 1024);
    }
  };
  int co = ((l4 + ((l16 >> 1) & 3)) & 3) << 3;
  int rba = (wm + l16) * 32 + co;
  int rbb = (wn + l16) * 32 + co;
  floatx4 acc[4][4] = {};
  stage(0, 0);
  __syncthreads();
  int NTt = K >> 5;
  for (int tt = 0; tt < NTt; ++tt) {
    int p = tt & 1;
    if (tt + 1 < NTt) stage(p ^ 1, (tt + 1) << 5);
    bf16x8 bfr[4];
#pragma unroll
    for (int nt = 0; nt < 4; nt++) bfr[nt] = *(const bf16x8*)&Bs[p][rbb + nt * 512];
    __builtin_amdgcn_s_setprio(1);
#pragma unroll
    for (int mt = 0; mt < 4; mt++) {
      bf16x8 a = *(const bf16x8*)&As[p][rba + mt * 512];
#pragma unroll
      for (int nt = 0; nt < 4; nt++)
        acc[mt][nt] = __builtin_amdgcn_mfma_f32_16x16x32_bf16(a, bfr[nt], acc[mt][nt], 0, 0, 0);
    }
    __builtin_amdgcn_s_setprio(0);
    __syncthreads();
  }
#pragma unroll
  for (int mt = 0; mt < 4; mt++)
#pragma unroll
    for (int nt = 0; nt < 4; nt++) {
      int col = n0 + wn + nt * 16 + l16;
      float bval = bias[col];
      if constexpr (SCATTER) {
        int which = col >> 10;
        int h = (col >> 6) & 15;
        int dh = col & 63;
        int rmask = (1 << rpb) - 1;
        if (which == 2) {
          int rw0 = m0 + wm + mt * 16 + l4 * 4;
          int b = rw0 >> rpb;
          int s = soff + (rw0 & rmask);
          bf16x4 o;
#pragma unroll
          for (int r = 0; r < 4; r++) o[r] = (bf16)(acc[mt][nt][r] + bval);
          *(bf16x4*)(vs + ((size_t)(b * NHEAD + h) * DHEAD + dh) * S_SEQ + s) = o;
        } else {
          bf16* dst = which == 0 ? qs : ks;
#pragma unroll
          for (int r = 0; r < 4; r++) {
            int rw = m0 + wm + mt * 16 + l4 * 4 + r;
            int b = rw >> rpb;
            int s = soff + (rw & rmask);
            dst[((size_t)(b * NHEAD + h) * S_SEQ + s) * DHEAD + dh] =
                (bf16)(acc[mt][nt][r] + bval);
          }
        }
      } else {
#pragma unroll
        for (int r = 0; r < 4; r++) {
          int rw = m0 + wm + mt * 16 + l4 * 4 + r;
          Cp[(size_t)rw * N + col] = (bf16)(acc[mt][nt][r] + bval);
        }
      }
    }
}

// ---------------------------------------------------------------- qkv post
// 2 tokens per block, 128 threads/token, 16 B/lane. Extra block ranges
// absorb Wout/cWout transposes (needed only by the out-GEMM).
//   [0,4608)      token pairs   [4608,4864) WoutT   [4864,5120) cWoutT
__global__ __launch_bounds__(256) void qkv_post(
    bf16* __restrict__ qs, bf16* __restrict__ ks,
    const int* __restrict__ mask, const float* __restrict__ rope,
    const int* __restrict__ anym,
    const float* __restrict__ g_q, const float* __restrict__ g_k,
    const float* __restrict__ cg_q, const float* __restrict__ cg_k,
    const float* __restrict__ Wout, const float* __restrict__ cWout,
    bf16* __restrict__ WoutT, bf16* __restrict__ cWoutT) {
  __shared__ bf16 tile[64][65];
  __shared__ float red[8];
  int blk = blockIdx.x, t = threadIdx.x;
  if (blk >= 4608) {
    int b = blk - 4608;
    if (b < 256) { transpose_job64(Wout, WoutT, 1024, 1024, b, tile); return; }
    b -= 256;
    transpose_job64(cWout, cWoutT, 1024, 1024, b, tile);
    return;
  }
  int tt = t & 127, tsel = t >> 7;
  int g = blk * 2 + tsel;                       // token id (x: <8192, ctx rest)
  bool is_ctx = g >= NBATCH * L_SEQ;
  int b, s;
  const float *gq, *gk;
  float mval;
  if (!is_ctx) {
    b = g >> 11;
    int l = g & 2047;
    s = l;
    mval = mask[(size_t)b * L_SEQ * L_SEQ + l] ? 1.f : 0.f;  // mask[b][0][l]
    gq = g_q; gk = g_k;
  } else {
    int gg = g - NBATCH * L_SEQ;
    b = gg >> 8;
    s = L_SEQ + (gg & 255);
    mval = anym[b] ? 1.f : 0.f;
    gq = cg_q; gk = cg_k;
  }
  int d0 = tt * 8;
  int h = tt >> 3, dh = (tt & 7) * 8;           // h*64+dh == d0
  size_t base = ((size_t)(b * NHEAD + h) * S_SEQ + s) * DHEAD + dh;
  bf16x8 q8 = *(const bf16x8*)(qs + base);
  bf16x8 k8 = *(const bf16x8*)(ks + base);
  float qv[8], kv[8], pq = 0.f, pk = 0.f;
#pragma unroll
  for (int i = 0; i < 8; i++) {
    qv[i] = (float)q8[i]; kv[i] = (float)k8[i];
    pq += qv[i] * qv[i];  pk += kv[i] * kv[i];
  }
  int w = t >> 6;                                // wave id 0..3
  for (int off = 32; off > 0; off >>= 1) {
    pq += __shfl_down(pq, off, 64);
    pk += __shfl_down(pk, off, 64);
  }
  if ((t & 63) == 0) { red[w] = pq; red[4 + w] = pk; }
  __syncthreads();
  float sq = red[tsel * 2] + red[tsel * 2 + 1];
  float sk = red[4 + tsel * 2] + red[4 + tsel * 2 + 1];
  float scq = rsqrtf(sq * (1.f / DMODEL) + RMS_EPS);
  float sck = rsqrtf(sk * (1.f / DMODEL) + RMS_EPS);
#pragma unroll
  for (int i = 0; i < 8; i++) {
    qv[i] *= scq * gq[d0 + i];
    kv[i] *= sck * gk[d0 + i];
  }
  if (!is_ctx) {
    // table: 64 entries PER TOKEN indexed by HEAD dim dh (cos even, sin odd)
    floatx4 ta = *(const floatx4*)&rope[((size_t)g) * 64 + dh];
    floatx4 tb = *(const floatx4*)&rope[((size_t)g) * 64 + dh + 4];
#pragma unroll
    for (int pr = 0; pr < 4; pr++) {
      float cc = pr < 2 ? ta[2 * pr] : tb[2 * (pr - 2)];
      float ss = pr < 2 ? ta[2 * pr + 1] : tb[2 * (pr - 2) + 1];
      float t0 = qv[2 * pr], t1 = qv[2 * pr + 1];
      qv[2 * pr]     = t0 * cc - t1 * ss;
      qv[2 * pr + 1] = t0 * ss + t1 * cc;
      t0 = kv[2 * pr]; t1 = kv[2 * pr + 1];
      kv[2 * pr]     = t0 * cc - t1 * ss;
      kv[2 * pr + 1] = t0 * ss + t1 * cc;
    }
  }
  bf16x8 qo, ko;
#pragma unroll
  for (int i = 0; i < 8; i++) {
    qo[i] = (bf16)fmaxf(qv[i], 0.f);
    ko[i] = (bf16)(fmaxf(kv[i], 0.f) * mval);
  }
  *(bf16x8*)(qs + base) = qo;
  *(bf16x8*)(ks + base) = ko;
}

// ---------------------------------------------------------------- vk (MFMA)
// vk partials: block (bh, chunk) writes its OWN slab vkw[bh][chunk][65*64]
// with plain coalesced stores (each element written by exactly one thread) —
// no atomics, no pre-zeroing. res_attn sums the VK_CH partials (L2-resident,
// 9 blocks share each bh).
#define VK_CH   12
#define VK_SPAN (S_SEQ / VK_CH)   // 192 = 6 K-steps of 32
#define VK_SLAB (65 * 64)         // 4160 f32 per partial
__global__ __launch_bounds__(256) void vk_mfma(
    const bf16* __restrict__ vT, const bf16* __restrict__ kf,
    float* __restrict__ vk) {
  __shared__ bf16 Vs[2][64][40];
  __shared__ bf16 Ks[2][64][40];   // Ks[d][s]
  int bh = blockIdx.x / VK_CH, chunk = blockIdx.x % VK_CH;
  int t = threadIdx.x, lane = t & 63, w = t >> 6;
  int l16 = lane & 15, l4 = lane >> 4;
  const bf16* vp = vT + (size_t)bh * DHEAD * S_SEQ;
  const bf16* kp = kf + (size_t)bh * S_SEQ * DHEAD;
  int s_begin = chunk * VK_SPAN;
  int ve = t >> 2, vso = (t & 3) * 8;        // v staging: row e, col offset
  int ks_s = t & 31, kd0 = (t >> 5) * 8;     // kf staging: s-slice, d-octet
  floatx4 acc[4] = {};
  float dsum[8] = {};
  bf16x8 vv = *(const bf16x8*)(vp + (size_t)ve * S_SEQ + s_begin + vso);
  bf16x8 kv = *(const bf16x8*)(kp + (size_t)(s_begin + ks_s) * DHEAD + kd0);
  for (int st = 0; st < VK_SPAN; st += 32) {
    int cur = (st >> 5) & 1;
    *(bf16x8*)&Vs[cur][ve][vso] = vv;
#pragma unroll
    for (int j = 0; j < 8; j++) {
      Ks[cur][kd0 + j][ks_s] = kv[j];
      dsum[j] += (float)kv[j];
    }
    if (st + 32 < VK_SPAN) {
      int s0 = s_begin + st + 32;
      vv = *(const bf16x8*)(vp + (size_t)ve * S_SEQ + s0 + vso);
      kv = *(const bf16x8*)(kp + (size_t)(s0 + ks_s) * DHEAD + kd0);
    }
    __syncthreads();
    bf16x8 af = *(const bf16x8*)&Vs[cur][w * 16 + l16][l4 * 8];
#pragma unroll
    for (int nt = 0; nt < 4; nt++) {
      bf16x8 bfr = *(const bf16x8*)&Ks[cur][nt * 16 + l16][l4 * 8];
      acc[nt] = __builtin_amdgcn_mfma_f32_16x16x32_bf16(af, bfr, acc[nt], 0, 0, 0);
    }
  }
  float* vkp_part = vk + ((size_t)bh * VK_CH + chunk) * VK_SLAB;
#pragma unroll
  for (int nt = 0; nt < 4; nt++)
#pragma unroll
    for (int r = 0; r < 4; r++)
      vkp_part[(w * 16 + l4 * 4 + r) * 64 + nt * 16 + l16] = acc[nt][r];
  // denom row e=64: reduce within each 32-lane half-wave (one d-octet each)
#pragma unroll
  for (int j = 0; j < 8; j++)
#pragma unroll
    for (int off = 16; off > 0; off >>= 1)
      dsum[j] += __shfl_down(dsum[j], off, 32);
  if ((lane & 31) == 0 && w == 0)
#pragma unroll
    for (int j = 0; j < 8; j++)
      vkp_part[64 * 64 + kd0 + j] = dsum[j];
  // kd0 covers 0..56 via (t>>5)*8 over both half-waves of wave 0? No:
  // kd0 = (t>>5)*8 for t in [0,64) gives {0,8}; waves 1..3 give 16..63.
  // So write from lane 0 of each half-wave across ALL waves:
  if ((lane & 31) == 0 && w != 0)
#pragma unroll
    for (int j = 0; j < 8; j++)
      vkp_part[64 * 64 + kd0 + j] = dsum[j];
}

// ---------------------------------------------------------------- res + div
// Stages Bs by summing the VK_CH per-chunk partials (replaces atomics+zero).
__global__ __launch_bounds__(256) void res_attn(
    const bf16* __restrict__ qf, const float* __restrict__ vk,
    bf16* __restrict__ attn_x, bf16* __restrict__ attn_c) {
  __shared__ bf16 Bs[80][72];
  __shared__ float sden[256];
  int bh = blockIdx.x / 9, mblk = blockIdx.x % 9;
  int b = bh >> 4, h = bh & 15;
  int t = threadIdx.x, lane = t & 63, w = t >> 6;
  const float* vkp = vk + (size_t)bh * VK_CH * VK_SLAB;
  for (int i = t; i < 80 * 64; i += 256) {
    int e = i >> 6, d = i & 63;
    float ssum = 0.f;
    if (e < 65) {
#pragma unroll
      for (int c = 0; c < VK_CH; c++) ssum += vkp[c * VK_SLAB + i];
    }
    Bs[e][d] = (bf16)ssum;
  }
  __syncthreads();
  int l16 = lane & 15, l4 = lane >> 4;
  const bf16* qbase = qf + (size_t)bh * S_SEQ * DHEAD;
  int q0w = mblk * 256 + w * 64;

  floatx4 acc[4][5] = {};
  bf16x8 af[4][2], bfr[5][2];
#pragma unroll
  for (int mt = 0; mt < 4; mt++) {
    int q = q0w + mt * 16 + l16;
    af[mt][0] = *(const bf16x8*)(qbase + (size_t)q * 64 + l4 * 8);
    af[mt][1] = *(const bf16x8*)(qbase + (size_t)q * 64 + 32 + l4 * 8);
  }
#pragma unroll
  for (int nt = 0; nt < 5; nt++) {
    bfr[nt][0] = *(const bf16x8*)&Bs[nt * 16 + l16][l4 * 8];
    bfr[nt][1] = *(const bf16x8*)&Bs[nt * 16 + l16][32 + l4 * 8];
  }
#pragma unroll
  for (int mt = 0; mt < 4; mt++)
#pragma unroll
    for (int nt = 0; nt < 5; nt++) {
      acc[mt][nt] = __builtin_amdgcn_mfma_f32_16x16x32_bf16(af[mt][0], bfr[nt][0], acc[mt][nt], 0, 0, 0);
      acc[mt][nt] = __builtin_amdgcn_mfma_f32_16x16x32_bf16(af[mt][1], bfr[nt][1], acc[mt][nt], 0, 0, 0);
    }
  // denominator: e=64 = col 0 of n-tile 4 (lanes with l16==0)
  if (l16 == 0) {
#pragma unroll
    for (int mt = 0; mt < 4; mt++)
#pragma unroll
      for (int r = 0; r < 4; r++)
        sden[w * 64 + mt * 16 + l4 * 4 + r] = acc[mt][4][r];
  }
  __syncthreads();
#pragma unroll
  for (int mt = 0; mt < 4; mt++)
#pragma unroll
    for (int r = 0; r < 4; r++) {
      float den = sden[w * 64 + mt * 16 + l4 * 4 + r] + LIN_EPS;
      float rden = 1.f / den;
      int q = q0w + mt * 16 + l4 * 4 + r;
#pragma unroll
      for (int nt = 0; nt < 4; nt++) {
        int dcol = nt * 16 + l16;
        float a = acc[mt][nt][r] * rden;
        if (q < L_SEQ)
          attn_x[((size_t)b * L_SEQ + q) * DMODEL + h * DHEAD + dcol] = (bf16)a;
        else
          attn_c[((size_t)b * C_SEQ + (q - L_SEQ)) * DMODEL + h * DHEAD + dcol] = (bf16)a;
      }
    }
}

// ---------------------------------------------------------------- final norm
// 2 rows/block, 128 threads/row, 16 B/lane in, 32 B/lane out (f32).
__global__ __launch_bounds__(256) void final_norm(
    const bf16* __restrict__ y_x, const bf16* __restrict__ y_c,
    const float* __restrict__ g_out, const float* __restrict__ cg_out,
    float* __restrict__ out) {
  __shared__ float red[8];
  int t = threadIdx.x;
  int tt = t & 127, tsel = t >> 7;
  int g = blockIdx.x * 2 + tsel;
  const bf16* src;
  const float* gv;
  if (g < NBATCH * L_SEQ) {
    src = y_x + (size_t)g * DMODEL; gv = g_out;
  } else {
    int gg = g - NBATCH * L_SEQ;
    src = y_c + (size_t)gg * DMODEL; gv = cg_out;
  }
  float* dst = out + (size_t)g * DMODEL;
  int d0 = tt * 8;
  bf16x8 y8 = *(const bf16x8*)(src + d0);
  float yv[8], p = 0.f;
#pragma unroll
  for (int i = 0; i < 8; i++) { yv[i] = (float)y8[i]; p += yv[i] * yv[i]; }
  int w = t >> 6;
  for (int off = 32; off > 0; off >>= 1) p += __shfl_down(p, off, 64);
  if ((t & 63) == 0) red[w] = p;
  __syncthreads();
  float ssum = red[tsel * 2] + red[tsel * 2 + 1];
  float sc = rsqrtf(ssum * (1.f / DMODEL) + RMS_EPS);
  floatx4 o0, o1;
#pragma unroll
  for (int i = 0; i < 4; i++) {
    o0[i] = yv[i] * sc * gv[d0 + i];
    o1[i] = yv[4 + i] * sc * gv[d0 + 4 + i];
  }
  *(floatx4*)(dst + d0) = o0;
  *(floatx4*)(dst + d0 + 4) = o1;
}

// ---------------------------------------------------------------- launch
extern "C" void kernel_launch(void* const* d_in, const int* in_sizes, int n_in,
                              void* d_out, int out_size, void* d_ws, size_t ws_size,
                              hipStream_t stream) {
  const float* x      = (const float*)d_in[0];
  const float* ctx    = (const float*)d_in[1];
  const int*   mask   = (const int*)d_in[2];
  const int*   spos   = (const int*)d_in[3];
  const float* Wqkv   = (const float*)d_in[4];
  const float* bqkv   = (const float*)d_in[5];
  const float* g_q    = (const float*)d_in[6];
  const float* g_k    = (const float*)d_in[7];
  const float* cWqkv  = (const float*)d_in[8];
  const float* cbqkv  = (const float*)d_in[9];
  const float* cg_q   = (const float*)d_in[10];
  const float* cg_k   = (const float*)d_in[11];
  const float* Wout   = (const float*)d_in[12];
  const float* bout   = (const float*)d_in[13];
  const float* g_out  = (const float*)d_in[14];
  const float* cWout  = (const float*)d_in[15];
  const float* cbout  = (const float*)d_in[16];
  const float* cg_out = (const float*)d_in[17];

  char* wsp = (char*)d_ws;
  size_t off = 0;
  auto alloc = [&](size_t bytes) -> void* {
    void* p = wsp + off;
    off += (bytes + 255) & ~(size_t)255;
    return p;
  };
  bf16* WqkvT  = (bf16*)alloc((size_t)3072 * 1024 * 2);
  bf16* cWqkvT = (bf16*)alloc((size_t)3072 * 1024 * 2);
  bf16* WoutT  = (bf16*)alloc((size_t)1024 * 1024 * 2);
  bf16* cWoutT = (bf16*)alloc((size_t)1024 * 1024 * 2);
  bf16* xbf    = (bf16*)alloc((size_t)NBATCH * L_SEQ * DMODEL * 2);
  bf16* cbf    = (bf16*)alloc((size_t)NBATCH * C_SEQ * DMODEL * 2);
  const size_t SLAB = (size_t)NBATCH * NHEAD * S_SEQ * DHEAD;  // 9,437,184
  bf16* qfs    = (bf16*)alloc(SLAB * 2);
  bf16* kfs    = (bf16*)alloc(SLAB * 2);
  bf16* vfs    = (bf16*)alloc(SLAB * 2);   // holds vT [bh][d][s]
  float* vkw   = (float*)alloc((size_t)64 * VK_CH * VK_SLAB * 4);  // 12.8 MB
  float* rope  = (float*)alloc((size_t)NBATCH * L_SEQ * 64 * 4);
  int* anym    = (int*)alloc(256);
  // attn aliases kf slab (dead after vk_mfma); y aliases v slab.
  bf16* attn_x = kfs;
  bf16* attn_c = kfs + (size_t)NBATCH * L_SEQ * DMODEL;
  bf16* y_x    = vfs;
  bf16* y_c    = vfs + (size_t)NBATCH * L_SEQ * DMODEL;

  // 1) prep (QKV-critical only): Wqkv/cWqkv transposes, converts, rope, anymask
  prep<<<8196, 256, 0, stream>>>(Wqkv, cWqkv, x, ctx, mask, spos,
                                 WqkvT, cWqkvT, xbf, cbf, rope, anym);

  // 2) QKV projections (x + ctx in one launch): 8-phase 256^2 schedule
  gemm_qkv8<<<dim3(12, 36), 512, 0, stream>>>(
      xbf, cbf, WqkvT, cWqkvT, bqkv, cbqkv,
      qfs, kfs, vfs, 1024, 32, 11, 0, 8, L_SEQ);

  // 3) qkv post (16 B/lane) + deferred Wout/cWout transposes
  qkv_post<<<5120, 256, 0, stream>>>(
      qfs, kfs, mask, rope, anym, g_q, g_k, cg_q, cg_k,
      Wout, cWout, WoutT, cWoutT);

  // 4) vk = vT kf via MFMA -> per-chunk partial slabs (no atomics)
  vk_mfma<<<64 * VK_CH, 256, 0, stream>>>(vfs, kfs, vkw);

  // 5) res = qf vk^T (summing partials), divide, scatter token-major
  res_attn<<<576, 256, 0, stream>>>(qfs, vkw, attn_x, attn_c);

  // 6) output projections (x + ctx in one launch), proven 128^2 2-phase
  gemm_bias<false><<<dim3(8, 72), 256, 0, stream>>>(
      attn_x, attn_c, WoutT, cWoutT, bout, cbout, y_x, y_c,
      nullptr, nullptr, nullptr, 1024, 1024, 64, 0, 0, 0, 0);

  // 7) final rmsnorm -> FLOAT32 d_out (x_out rows then c_out rows)
  final_norm<<<4608, 256, 0, stream>>>(
      y_x, y_c, g_out, cg_out, (float*)d_out);
}